// Round 7
// baseline (3372.826 us; speedup 1.0000x reference)
//
#include <hip/hip_runtime.h>
#include <hip/hip_bf16.h>

#define C 192
#define T 4096
#define L 16
#define BATCH 16
#define NT 128         // t-positions per block
#define XR 136         // x tile rows incl. halo 4+4
#define CPAD 200       // padded channel stride in LDS (shorts) -> 400B rows
#define SMEM_BYTES (2 * XR * CPAD * 2)   // xhi + xlo: 108,800 B

typedef __attribute__((ext_vector_type(8))) short short8;
typedef __attribute__((ext_vector_type(4))) short short4v;
typedef __attribute__((ext_vector_type(4))) float f32x4;

__device__ __forceinline__ short f2bf(float v) {
    __hip_bfloat16 h = __float2bfloat16(v);
    return *reinterpret_cast<const short*>(&h);
}
__device__ __forceinline__ float bf2f(short s) {
    unsigned u = ((unsigned)(unsigned short)s) << 16;
    float f;
    __builtin_memcpy(&f, &u, 4);
    return f;
}

__device__ __forceinline__ float gatefn(float x1, float x2) {
    float ax = fabsf(x1);
    float e  = __expf(-2.f * ax);
    float th = __builtin_copysignf((1.f - e) / (1.f + e), x1);
    float sg = 1.f / (1.f + __expf(-x2));
    return th * sg;
}

// ---- weight pre-format with hi/lo bf16 split (Dekker: v-hi exact in fp32) ----
__global__ __launch_bounds__(256)
void fmt_win(const float* __restrict__ W, short* __restrict__ dhi,
             short* __restrict__ dlo, int total) {
    int gid = blockIdx.x * 256 + threadIdx.x;
    if (gid >= total) return;
    int lane = gid & 63; int r = gid >> 6;
    int icc = r % 6; r /= 6;
    int mt  = r % 24; r /= 24;
    int tap = r % 5;  int l = r / 5;
    int oc  = mt * 16 + (lane & 15);
    int ic0 = icc * 32 + (lane >> 4) * 8;
    const float* s = W + ((size_t)((l * 384 + oc) * 192 + ic0)) * 5 + tap;
    short8 vh, vl;
    #pragma unroll
    for (int i = 0; i < 8; ++i) {
        float v = s[(size_t)i * 5];
        short h = f2bf(v);
        vh[i] = h;
        vl[i] = f2bf(v - bf2f(h));
    }
    *reinterpret_cast<short8*>(dhi + (size_t)gid * 8) = vh;
    *reinterpret_cast<short8*>(dlo + (size_t)gid * 8) = vl;
}

__global__ __launch_bounds__(256)
void fmt_w11(const float* __restrict__ W, short* __restrict__ dhi,
             short* __restrict__ dlo, int mtc, int total) {
    int gid = blockIdx.x * 256 + threadIdx.x;
    if (gid >= total) return;
    int lane = gid & 63; int r = gid >> 6;
    int icc = r % 6; r /= 6;
    int mt  = r % mtc; int l = r / mtc;
    int oc  = mt * 16 + (lane & 15);
    int ic0 = icc * 32 + (lane >> 4) * 8;
    const float* s = W + (size_t)(l * (mtc * 16) + oc) * 192 + ic0;
    short8 vh, vl;
    #pragma unroll
    for (int i = 0; i < 8; ++i) {
        float v = s[i];
        short h = f2bf(v);
        vh[i] = h;
        vl[i] = f2bf(v - bf2f(h));
    }
    *reinterpret_cast<short8*>(dhi + (size_t)gid * 8) = vh;
    *reinterpret_cast<short8*>(dlo + (size_t)gid * 8) = vl;
}

// ---- one-time transpose+split: x fp32 [b][c][t] -> hi/lo bf16 planes [b][t][c] ----
__global__ __launch_bounds__(256)
void xpose(const float* __restrict__ x, short* __restrict__ xh, short* __restrict__ xl)
{
    __shared__ float tile[C][65];
    const int t0 = blockIdx.x * 64;
    const int b  = blockIdx.y;
    const float* xg = x + (size_t)b * C * T;
    for (int idx = threadIdx.x; idx < C * 16; idx += 256) {
        int ch = idx & 15, c = idx >> 4;
        f32x4 v = *reinterpret_cast<const f32x4*>(xg + (size_t)c * T + t0 + ch * 4);
        #pragma unroll
        for (int q = 0; q < 4; ++q) tile[c][ch * 4 + q] = v[q];
    }
    __syncthreads();
    for (int idx = threadIdx.x; idx < 64 * 24; idx += 256) {
        int cc = idx % 24, t = idx / 24;
        short8 h8, l8;
        #pragma unroll
        for (int i = 0; i < 8; ++i) {
            float v = tile[cc * 8 + i][t];
            short h = f2bf(v);
            h8[i] = h;
            l8[i] = f2bf(v - bf2f(h));
        }
        size_t off = (size_t)b * T * C + (size_t)(t0 + t) * C + cc * 8;
        *reinterpret_cast<short8*>(xh + off) = h8;
        *reinterpret_cast<short8*>(xl + off) = l8;
    }
}

// ---- fused WaveNet layer: x master is hi/lo bf16 [b][t][c] planes in ws ----
// 16 waves: wm=wid&3 (3 mt-pairs), wn=wid>>2 in 0..3 (2 nt-tiles each)
template<bool FIRST, bool LAST>
__global__ __launch_bounds__(1024, 4)
void wnet_layer(const short* __restrict__ xhin, const short* __restrict__ xlin,
                short* __restrict__ xhout, short* __restrict__ xlout,
                const float* __restrict__ mask,
                const short* __restrict__ wchi, const short* __restrict__ wclo,
                const float* __restrict__ bc,
                const short* __restrict__ wrhi, const short* __restrict__ wrlo,
                const float* __restrict__ br,
                float* __restrict__ o)
{
    extern __shared__ __align__(16) char smem_raw[];
    short* xhi = reinterpret_cast<short*>(smem_raw);
    short* xlo = xhi + XR * CPAD;

    const int tid = threadIdx.x;
    const int t0  = blockIdx.x * NT;
    const int b   = blockIdx.y;

    // ---- stage: pure 16B vector copies, no conversion, no transpose ----
    {
        const short* gh = xhin + (size_t)b * T * C;
        const short* gl = xlin + (size_t)b * T * C;
        for (int idx = tid; idx < 2 * XR * 24; idx += 1024) {
            int chunk = idx % 24;
            int r     = (idx / 24) % XR;
            int plane = idx / (24 * XR);
            int t = t0 - 4 + r;
            short8 v = {};
            if (t >= 0 && t < T)
                v = *reinterpret_cast<const short8*>(
                        (plane ? gl : gh) + (size_t)t * C + chunk * 8);
            *reinterpret_cast<short8*>((plane ? xlo : xhi) + r * CPAD + chunk * 8) = v;
        }
    }
    __syncthreads();

    const int lane = tid & 63;
    const int wid  = tid >> 6;
    const int wm   = wid & 3;
    const int wn   = wid >> 2;      // 0..3
    const int col  = lane & 15;
    const int sg   = lane >> 4;

    // ---- residual x pre-read from LDS (early; must precede gate overwrite) ----
    float xres[3][2][4];
    if constexpr (!LAST) {
        #pragma unroll
        for (int p = 0; p < 2; ++p) {
            const int row = (wn * 2 + p) * 16 + col + 4;
            #pragma unroll
            for (int j = 0; j < 3; ++j) {
                const int ch = (wm * 3 + j) * 16 + sg * 4;
                short4v h4 = *reinterpret_cast<const short4v*>(&xhi[row * CPAD + ch]);
                short4v l4 = *reinterpret_cast<const short4v*>(&xlo[row * CPAD + ch]);
                #pragma unroll
                for (int i = 0; i < 4; ++i) xres[j][p][i] = bf2f(h4[i]) + bf2f(l4[i]);
            }
        }
    }

    // ---- conv K5 (3-pass Dekker split): oc = (h*12+wm*3+j)*16 + 4*sg+i ----
    f32x4 acc[3][2][2];
    #pragma unroll
    for (int j = 0; j < 3; ++j)
    #pragma unroll
    for (int h = 0; h < 2; ++h) {
        f32x4 bv = *reinterpret_cast<const f32x4*>(bc + (h * 12 + wm * 3 + j) * 16 + sg * 4);
        #pragma unroll
        for (int p = 0; p < 2; ++p) acc[j][h][p] = bv;
    }

    for (int tap = 0; tap < 5; ++tap) {
        #pragma unroll
        for (int icc = 0; icc < 6; ++icc) {
            short8 bh[2], bl[2];
            #pragma unroll
            for (int p = 0; p < 2; ++p) {
                int off = ((wn * 2 + p) * 16 + col + tap + 2) * CPAD + icc * 32 + sg * 8;
                bh[p] = *reinterpret_cast<const short8*>(&xhi[off]);
                bl[p] = *reinterpret_cast<const short8*>(&xlo[off]);
            }
            #pragma unroll
            for (int h = 0; h < 2; ++h)
            #pragma unroll
            for (int j = 0; j < 3; ++j) {
                const int mt = h * 12 + wm * 3 + j;
                const size_t wo = ((size_t)((tap * 24 + mt) * 6 + icc) * 64 + lane) * 8;
                short8 ah = *reinterpret_cast<const short8*>(wchi + wo);
                short8 al = *reinterpret_cast<const short8*>(wclo + wo);
                #pragma unroll
                for (int p = 0; p < 2; ++p) {
                    acc[j][h][p] = __builtin_amdgcn_mfma_f32_16x16x32_bf16(ah, bh[p], acc[j][h][p], 0, 0, 0);
                    acc[j][h][p] = __builtin_amdgcn_mfma_f32_16x16x32_bf16(al, bh[p], acc[j][h][p], 0, 0, 0);
                    acc[j][h][p] = __builtin_amdgcn_mfma_f32_16x16x32_bf16(ah, bl[p], acc[j][h][p], 0, 0, 0);
                }
            }
        }
    }
    __syncthreads();   // conv + residual LDS reads done before acts overwrite

    // ---- gate -> acts hi/lo (reuse xhi/xlo, rows [0,NT)) ----
    #pragma unroll
    for (int j = 0; j < 3; ++j)
    #pragma unroll
    for (int p = 0; p < 2; ++p) {
        const int tt = (wn * 2 + p) * 16 + col;
        const int ch = (wm * 3 + j) * 16 + sg * 4;
        float av[4];
        #pragma unroll
        for (int i = 0; i < 4; ++i)
            av[i] = gatefn(acc[j][0][p][i], acc[j][1][p][i]);
        #pragma unroll
        for (int i2 = 0; i2 < 2; ++i2) {
            short h0 = f2bf(av[i2 * 2]);
            short h1 = f2bf(av[i2 * 2 + 1]);
            short l0 = f2bf(av[i2 * 2]     - bf2f(h0));
            short l1 = f2bf(av[i2 * 2 + 1] - bf2f(h1));
            unsigned ph = (unsigned)(unsigned short)h0 | ((unsigned)(unsigned short)h1 << 16);
            unsigned pl = (unsigned)(unsigned short)l0 | ((unsigned)(unsigned short)l1 << 16);
            *reinterpret_cast<unsigned*>(&xhi[tt * CPAD + ch + i2 * 2]) = ph;
            *reinterpret_cast<unsigned*>(&xlo[tt * CPAD + ch + i2 * 2]) = pl;
        }
    }
    __syncthreads();

    // ---- 1x1 (3-pass split: Wh*ah + Wl*ah + Wh*al) ----
    constexpr int HN = LAST ? 1 : 2;
    f32x4 a2[3][HN][2];
    #pragma unroll
    for (int j = 0; j < 3; ++j)
    #pragma unroll
    for (int h = 0; h < HN; ++h) {
        f32x4 bv = *reinterpret_cast<const f32x4*>(br + (h * 12 + wm * 3 + j) * 16 + sg * 4);
        #pragma unroll
        for (int p = 0; p < 2; ++p) a2[j][h][p] = bv;
    }
    #pragma unroll
    for (int icc = 0; icc < 6; ++icc) {
        short8 bah[2], bal[2];
        #pragma unroll
        for (int p = 0; p < 2; ++p) {
            int off = ((wn * 2 + p) * 16 + col) * CPAD + icc * 32 + sg * 8;
            bah[p] = *reinterpret_cast<const short8*>(&xhi[off]);
            bal[p] = *reinterpret_cast<const short8*>(&xlo[off]);
        }
        #pragma unroll
        for (int h = 0; h < HN; ++h)
        #pragma unroll
        for (int j = 0; j < 3; ++j) {
            const int mt = h * 12 + wm * 3 + j;
            const size_t wo = ((size_t)(mt * 6 + icc) * 64 + lane) * 8;
            short8 rh = *reinterpret_cast<const short8*>(wrhi + wo);
            short8 rl = *reinterpret_cast<const short8*>(wrlo + wo);
            #pragma unroll
            for (int p = 0; p < 2; ++p) {
                a2[j][h][p] = __builtin_amdgcn_mfma_f32_16x16x32_bf16(rh, bah[p], a2[j][h][p], 0, 0, 0);
                a2[j][h][p] = __builtin_amdgcn_mfma_f32_16x16x32_bf16(rl, bah[p], a2[j][h][p], 0, 0, 0);
                a2[j][h][p] = __builtin_amdgcn_mfma_f32_16x16x32_bf16(rh, bal[p], a2[j][h][p], 0, 0, 0);
            }
        }
    }

    // ---- epilogue ----
    #pragma unroll
    for (int p = 0; p < 2; ++p) {
        const int tt = (wn * 2 + p) * 16 + col;
        const int t  = t0 + tt;
        const float mv = mask[(size_t)b * T + t];
        #pragma unroll
        for (int j = 0; j < 3; ++j) {
            const int ch = (wm * 3 + j) * 16 + sg * 4;
            float* op = o + ((size_t)b * C + ch) * T + t;
            if constexpr (LAST) {
                #pragma unroll
                for (int i = 0; i < 4; ++i)
                    op[(size_t)i * T] = (op[(size_t)i * T] + a2[j][0][p][i]) * mv;
            } else {
                short4v h4, l4;
                #pragma unroll
                for (int i = 0; i < 4; ++i) {
                    float nx = (xres[j][p][i] + a2[j][0][p][i]) * mv;
                    short h = f2bf(nx);
                    h4[i] = h;
                    l4[i] = f2bf(nx - bf2f(h));
                }
                size_t off = (size_t)b * T * C + (size_t)t * C + ch;
                *reinterpret_cast<short4v*>(xhout + off) = h4;
                *reinterpret_cast<short4v*>(xlout + off) = l4;
                #pragma unroll
                for (int i = 0; i < 4; ++i) {
                    if constexpr (FIRST) op[(size_t)i * T] = a2[j][1][p][i];
                    else                 op[(size_t)i * T] += a2[j][1][p][i];
                }
            }
        }
    }
}

#define WIN_STRIDE ((size_t)5 * 24 * 6 * 64 * 8)
#define WRS_STRIDE ((size_t)24 * 6 * 64 * 8)

extern "C" void kernel_launch(void* const* d_in, const int* in_sizes, int n_in,
                              void* d_out, int out_size, void* d_ws, size_t ws_size,
                              hipStream_t stream)
{
    const float* x      = (const float*)d_in[0];
    const float* mask   = (const float*)d_in[1];
    const float* W_in   = (const float*)d_in[2];
    const float* b_in   = (const float*)d_in[3];
    const float* W_rs   = (const float*)d_in[4];
    const float* b_rs   = (const float*)d_in[5];
    const float* W_last = (const float*)d_in[6];
    const float* b_last = (const float*)d_in[7];
    float* o = (float*)d_out;

    const size_t WIN_N = (size_t)L * WIN_STRIDE;
    const size_t WRS_N = (size_t)(L - 1) * WRS_STRIDE;
    const size_t WL_N  = (size_t)12 * 6 * 64 * 8;
    const size_t P     = (size_t)BATCH * T * C;      // plane elems (shorts)
    short* wchi = (short*)d_ws;
    short* wclo = wchi + WIN_N;
    short* wrhi = wclo + WIN_N;
    short* wrlo = wrhi + WRS_N;
    short* wlhi = wrlo + WRS_N;
    short* wllo = wlhi + WL_N;
    short* xah  = wllo + WL_N;
    short* xal  = xah + P;
    short* xbh  = xal + P;
    short* xbl  = xbh + P;

    {
        int tw = (int)(L * 5 * 24 * 6 * 64);
        fmt_win<<<(tw + 255) / 256, 256, 0, stream>>>(W_in, wchi, wclo, tw);
        int tr = (int)((L - 1) * 24 * 6 * 64);
        fmt_w11<<<(tr + 255) / 256, 256, 0, stream>>>(W_rs, wrhi, wrlo, 24, tr);
        int tl = (int)(12 * 6 * 64);
        fmt_w11<<<(tl + 255) / 256, 256, 0, stream>>>(W_last, wlhi, wllo, 12, tl);
        xpose<<<dim3(T / 64, BATCH), 256, 0, stream>>>(x, xah, xal);
    }

    (void)hipFuncSetAttribute(reinterpret_cast<const void*>(&wnet_layer<true, false>),
                              hipFuncAttributeMaxDynamicSharedMemorySize, SMEM_BYTES);
    (void)hipFuncSetAttribute(reinterpret_cast<const void*>(&wnet_layer<false, false>),
                              hipFuncAttributeMaxDynamicSharedMemorySize, SMEM_BYTES);
    (void)hipFuncSetAttribute(reinterpret_cast<const void*>(&wnet_layer<false, true>),
                              hipFuncAttributeMaxDynamicSharedMemorySize, SMEM_BYTES);

    dim3 grid(T / NT, BATCH);
    dim3 block(1024);

    short* curh = xah; short* curl = xal;
    short* nxth = xbh; short* nxtl = xbl;

    wnet_layer<true, false><<<grid, block, SMEM_BYTES, stream>>>(
        curh, curl, nxth, nxtl, mask,
        wchi, wclo, b_in, wrhi, wrlo, b_rs, o);
    { short* t1 = curh; curh = nxth; nxth = t1;
      short* t2 = curl; curl = nxtl; nxtl = t2; }

    for (int i = 1; i < L - 1; ++i) {
        wnet_layer<false, false><<<grid, block, SMEM_BYTES, stream>>>(
            curh, curl, nxth, nxtl, mask,
            wchi + (size_t)i * WIN_STRIDE, wclo + (size_t)i * WIN_STRIDE,
            b_in + (size_t)i * 2 * C,
            wrhi + (size_t)i * WRS_STRIDE, wrlo + (size_t)i * WRS_STRIDE,
            b_rs + (size_t)i * 2 * C, o);
        { short* t1 = curh; curh = nxth; nxth = t1;
          short* t2 = curl; curl = nxtl; nxtl = t2; }
    }

    wnet_layer<false, true><<<grid, block, SMEM_BYTES, stream>>>(
        curh, curl, nullptr, nullptr, mask,
        wchi + (size_t)(L - 1) * WIN_STRIDE, wclo + (size_t)(L - 1) * WIN_STRIDE,
        b_in + (size_t)(L - 1) * 2 * C,
        wlhi, wllo, b_last, o);
}

// Round 8
// 2928.999 us; speedup vs baseline: 1.1515x; 1.1515x over previous
//
#include <hip/hip_runtime.h>
#include <hip/hip_bf16.h>

#define C 192
#define T 4096
#define L 16
#define BATCH 16
#define NT 128         // t-positions per block
#define XR 136         // x tile rows incl. halo 4+4
#define CPAD 200       // padded channel stride in LDS (shorts) -> 400B rows
#define SMEM_BYTES (2 * XR * CPAD * 2)   // xhi + xlo: 108,800 B

#define CONV_TAP_STRIDE 73728   // elems: 24*6*512
#define MT_STRIDE       3072    // 6*512
#define ICC_STRIDE      512

typedef __attribute__((ext_vector_type(8))) short short8;
typedef __attribute__((ext_vector_type(4))) short short4v;
typedef __attribute__((ext_vector_type(4))) float f32x4;

__device__ __forceinline__ short f2bf(float v) {
    __hip_bfloat16 h = __float2bfloat16(v);
    return *reinterpret_cast<const short*>(&h);
}
__device__ __forceinline__ float bf2f(short s) {
    unsigned u = ((unsigned)(unsigned short)s) << 16;
    float f;
    __builtin_memcpy(&f, &u, 4);
    return f;
}

__device__ __forceinline__ float gatefn(float x1, float x2) {
    float ax = fabsf(x1);
    float e  = __expf(-2.f * ax);
    float th = __builtin_copysignf((1.f - e) / (1.f + e), x1);
    float sg = 1.f / (1.f + __expf(-x2));
    return th * sg;
}

// ---- weight pre-format with hi/lo bf16 split (Dekker: v-hi exact in fp32) ----
__global__ __launch_bounds__(256)
void fmt_win(const float* __restrict__ W, short* __restrict__ dhi,
             short* __restrict__ dlo, int total) {
    int gid = blockIdx.x * 256 + threadIdx.x;
    if (gid >= total) return;
    int lane = gid & 63; int r = gid >> 6;
    int icc = r % 6; r /= 6;
    int mt  = r % 24; r /= 24;
    int tap = r % 5;  int l = r / 5;
    int oc  = mt * 16 + (lane & 15);
    int ic0 = icc * 32 + (lane >> 4) * 8;
    const float* s = W + ((size_t)((l * 384 + oc) * 192 + ic0)) * 5 + tap;
    short8 vh, vl;
    #pragma unroll
    for (int i = 0; i < 8; ++i) {
        float v = s[(size_t)i * 5];
        short h = f2bf(v);
        vh[i] = h;
        vl[i] = f2bf(v - bf2f(h));
    }
    *reinterpret_cast<short8*>(dhi + (size_t)gid * 8) = vh;
    *reinterpret_cast<short8*>(dlo + (size_t)gid * 8) = vl;
}

__global__ __launch_bounds__(256)
void fmt_w11(const float* __restrict__ W, short* __restrict__ dhi,
             short* __restrict__ dlo, int mtc, int total) {
    int gid = blockIdx.x * 256 + threadIdx.x;
    if (gid >= total) return;
    int lane = gid & 63; int r = gid >> 6;
    int icc = r % 6; r /= 6;
    int mt  = r % mtc; int l = r / mtc;
    int oc  = mt * 16 + (lane & 15);
    int ic0 = icc * 32 + (lane >> 4) * 8;
    const float* s = W + (size_t)(l * (mtc * 16) + oc) * 192 + ic0;
    short8 vh, vl;
    #pragma unroll
    for (int i = 0; i < 8; ++i) {
        float v = s[i];
        short h = f2bf(v);
        vh[i] = h;
        vl[i] = f2bf(v - bf2f(h));
    }
    *reinterpret_cast<short8*>(dhi + (size_t)gid * 8) = vh;
    *reinterpret_cast<short8*>(dlo + (size_t)gid * 8) = vl;
}

// ---- one-time transpose+split: x fp32 [b][c][t] -> hi/lo bf16 planes [b][t][c] ----
__global__ __launch_bounds__(256)
void xpose(const float* __restrict__ x, short* __restrict__ xh, short* __restrict__ xl)
{
    __shared__ float tile[C][65];
    const int t0 = blockIdx.x * 64;
    const int b  = blockIdx.y;
    const float* xg = x + (size_t)b * C * T;
    for (int idx = threadIdx.x; idx < C * 16; idx += 256) {
        int ch = idx & 15, c = idx >> 4;
        f32x4 v = *reinterpret_cast<const f32x4*>(xg + (size_t)c * T + t0 + ch * 4);
        #pragma unroll
        for (int q = 0; q < 4; ++q) tile[c][ch * 4 + q] = v[q];
    }
    __syncthreads();
    for (int idx = threadIdx.x; idx < 64 * 24; idx += 256) {
        int cc = idx % 24, t = idx / 24;
        short8 h8, l8;
        #pragma unroll
        for (int i = 0; i < 8; ++i) {
            float v = tile[cc * 8 + i][t];
            short h = f2bf(v);
            h8[i] = h;
            l8[i] = f2bf(v - bf2f(h));
        }
        size_t off = (size_t)b * T * C + (size_t)(t0 + t) * C + cc * 8;
        *reinterpret_cast<short8*>(xh + off) = h8;
        *reinterpret_cast<short8*>(xl + off) = l8;
    }
}

// ---- fused WaveNet layer: x master is hi/lo bf16 [b][t][c] planes in ws ----
// 8 waves: wm=wid&3 (3 mt-pairs), wn=wid>>2 (4 nt-subtiles each)
// Conv/1x1 inner loops: software-pipelined weights (hi double-buffered,
// lo demand-loaded with pass-1 MFMA as latency cover).
template<bool FIRST, bool LAST>
__global__ __launch_bounds__(512, 2)
void wnet_layer(const short* __restrict__ xhin, const short* __restrict__ xlin,
                short* __restrict__ xhout, short* __restrict__ xlout,
                const float* __restrict__ mask,
                const short* __restrict__ wchi, const short* __restrict__ wclo,
                const float* __restrict__ bc,
                const short* __restrict__ wrhi, const short* __restrict__ wrlo,
                const float* __restrict__ br,
                float* __restrict__ o)
{
    extern __shared__ __align__(16) char smem_raw[];
    short* xhi = reinterpret_cast<short*>(smem_raw);
    short* xlo = xhi + XR * CPAD;

    const int tid = threadIdx.x;
    const int t0  = blockIdx.x * NT;
    const int b   = blockIdx.y;

    // ---- stage: pure 16B vector copies ----
    {
        const short* gh = xhin + (size_t)b * T * C;
        const short* gl = xlin + (size_t)b * T * C;
        for (int idx = tid; idx < 2 * XR * 24; idx += 512) {
            int chunk = idx % 24;
            int r     = (idx / 24) % XR;
            int plane = idx / (24 * XR);
            int t = t0 - 4 + r;
            short8 v = {};
            if (t >= 0 && t < T)
                v = *reinterpret_cast<const short8*>(
                        (plane ? gl : gh) + (size_t)t * C + chunk * 8);
            *reinterpret_cast<short8*>((plane ? xlo : xhi) + r * CPAD + chunk * 8) = v;
        }
    }
    __syncthreads();

    const int lane = tid & 63;
    const int wid  = tid >> 6;
    const int wm   = wid & 3;
    const int wn   = wid >> 2;      // 0..1
    const int col  = lane & 15;
    const int sg   = lane >> 4;

    // per-(h*3+j) weight element offsets (sans tap/icc)
    int wbase[6];
    #pragma unroll
    for (int q = 0; q < 6; ++q) {
        int h = q / 3, j = q % 3;
        int mt = h * 12 + wm * 3 + j;
        wbase[q] = mt * MT_STRIDE + lane * 8;
    }

    // ---- conv K5, 3-pass Dekker split, pipelined ----
    f32x4 acc[3][2][4];
    #pragma unroll
    for (int j = 0; j < 3; ++j)
    #pragma unroll
    for (int h = 0; h < 2; ++h) {
        f32x4 bv = *reinterpret_cast<const f32x4*>(bc + (h * 12 + wm * 3 + j) * 16 + sg * 4);
        #pragma unroll
        for (int p = 0; p < 4; ++p) acc[j][h][p] = bv;
    }

    short8 hA[6], hB[6];
    #pragma unroll
    for (int q = 0; q < 6; ++q)
        hA[q] = *reinterpret_cast<const short8*>(wchi + wbase[q]);   // (tap0,icc0)

    auto convstep = [&](int icc, short8 (&cur)[6], short8 (&nxt)[6],
                        size_t tapoff, size_t ntapoff, int tap) {
        // 1. demand lo for this step (consumed in pass 2)
        short8 lo6[6];
        #pragma unroll
        for (int q = 0; q < 6; ++q)
            lo6[q] = *reinterpret_cast<const short8*>(
                wclo + tapoff + (size_t)icc * ICC_STRIDE + wbase[q]);
        // 2. b-frags (LDS)
        short8 bh[4], bl[4];
        #pragma unroll
        for (int p = 0; p < 4; ++p) {
            int off = ((wn * 4 + p) * 16 + col + tap + 2) * CPAD + icc * 32 + sg * 8;
            bh[p] = *reinterpret_cast<const short8*>(&xhi[off]);
            bl[p] = *reinterpret_cast<const short8*>(&xlo[off]);
        }
        // 3. prefetch next step's hi weights
        size_t noff = (icc == 5) ? ntapoff : tapoff + (size_t)(icc + 1) * ICC_STRIDE;
        #pragma unroll
        for (int q = 0; q < 6; ++q)
            nxt[q] = *reinterpret_cast<const short8*>(wchi + noff + wbase[q]);
        // 4. pass 1: hi*hi  (covers the lo loads' L2 latency)
        #pragma unroll
        for (int h = 0; h < 2; ++h)
        #pragma unroll
        for (int j = 0; j < 3; ++j)
        #pragma unroll
        for (int p = 0; p < 4; ++p)
            acc[j][h][p] = __builtin_amdgcn_mfma_f32_16x16x32_bf16(
                cur[h * 3 + j], bh[p], acc[j][h][p], 0, 0, 0);
        // 5. pass 2: lo*hi
        #pragma unroll
        for (int h = 0; h < 2; ++h)
        #pragma unroll
        for (int j = 0; j < 3; ++j)
        #pragma unroll
        for (int p = 0; p < 4; ++p)
            acc[j][h][p] = __builtin_amdgcn_mfma_f32_16x16x32_bf16(
                lo6[h * 3 + j], bh[p], acc[j][h][p], 0, 0, 0);
        // 6. pass 3: hi*lo
        #pragma unroll
        for (int h = 0; h < 2; ++h)
        #pragma unroll
        for (int j = 0; j < 3; ++j)
        #pragma unroll
        for (int p = 0; p < 4; ++p)
            acc[j][h][p] = __builtin_amdgcn_mfma_f32_16x16x32_bf16(
                cur[h * 3 + j], bl[p], acc[j][h][p], 0, 0, 0);
    };

    for (int tap = 0; tap < 5; ++tap) {
        const size_t tapoff  = (size_t)tap * CONV_TAP_STRIDE;
        const size_t ntapoff = (size_t)(tap < 4 ? tap + 1 : 4) * CONV_TAP_STRIDE;
        #pragma unroll
        for (int ih = 0; ih < 3; ++ih) {
            convstep(2 * ih,     hA, hB, tapoff, ntapoff, tap);
            convstep(2 * ih + 1, hB, hA, tapoff, ntapoff, tap);
        }
    }

    // ---- residual x pre-read from LDS (before acts overwrite) ----
    float xres[3][4][4];
    if constexpr (!LAST) {
        #pragma unroll
        for (int p = 0; p < 4; ++p) {
            const int row = (wn * 4 + p) * 16 + col + 4;
            #pragma unroll
            for (int j = 0; j < 3; ++j) {
                const int ch = (wm * 3 + j) * 16 + sg * 4;
                short4v h4 = *reinterpret_cast<const short4v*>(&xhi[row * CPAD + ch]);
                short4v l4 = *reinterpret_cast<const short4v*>(&xlo[row * CPAD + ch]);
                #pragma unroll
                for (int i = 0; i < 4; ++i) xres[j][p][i] = bf2f(h4[i]) + bf2f(l4[i]);
            }
        }
    }
    __syncthreads();   // conv + residual LDS reads done before acts overwrite

    // ---- gate -> acts hi/lo (reuse xhi/xlo, rows [0,NT)) ----
    #pragma unroll
    for (int j = 0; j < 3; ++j)
    #pragma unroll
    for (int p = 0; p < 4; ++p) {
        const int tt = (wn * 4 + p) * 16 + col;
        const int ch = (wm * 3 + j) * 16 + sg * 4;
        float av[4];
        #pragma unroll
        for (int i = 0; i < 4; ++i)
            av[i] = gatefn(acc[j][0][p][i], acc[j][1][p][i]);
        #pragma unroll
        for (int i2 = 0; i2 < 2; ++i2) {
            short h0 = f2bf(av[i2 * 2]);
            short h1 = f2bf(av[i2 * 2 + 1]);
            short l0 = f2bf(av[i2 * 2]     - bf2f(h0));
            short l1 = f2bf(av[i2 * 2 + 1] - bf2f(h1));
            unsigned ph = (unsigned)(unsigned short)h0 | ((unsigned)(unsigned short)h1 << 16);
            unsigned pl = (unsigned)(unsigned short)l0 | ((unsigned)(unsigned short)l1 << 16);
            *reinterpret_cast<unsigned*>(&xhi[tt * CPAD + ch + i2 * 2]) = ph;
            *reinterpret_cast<unsigned*>(&xlo[tt * CPAD + ch + i2 * 2]) = pl;
        }
    }
    __syncthreads();

    // ---- 1x1 (3-pass split), pipelined over 6 icc steps ----
    constexpr int HN = LAST ? 1 : 2;
    constexpr int NQ = HN * 3;
    f32x4 a2[3][HN][4];
    #pragma unroll
    for (int j = 0; j < 3; ++j)
    #pragma unroll
    for (int h = 0; h < HN; ++h) {
        f32x4 bv = *reinterpret_cast<const f32x4*>(br + (h * 12 + wm * 3 + j) * 16 + sg * 4);
        #pragma unroll
        for (int p = 0; p < 4; ++p) a2[j][h][p] = bv;
    }

    short8 rA[NQ], rB[NQ];
    #pragma unroll
    for (int q = 0; q < NQ; ++q)
        rA[q] = *reinterpret_cast<const short8*>(wrhi + wbase[q]);   // icc=0

    auto r1step = [&](int icc, short8 (&cur)[NQ], short8 (&nxt)[NQ]) {
        short8 lo6[NQ];
        #pragma unroll
        for (int q = 0; q < NQ; ++q)
            lo6[q] = *reinterpret_cast<const short8*>(
                wrlo + (size_t)icc * ICC_STRIDE + wbase[q]);
        short8 bah[4], bal[4];
        #pragma unroll
        for (int p = 0; p < 4; ++p) {
            int off = ((wn * 4 + p) * 16 + col) * CPAD + icc * 32 + sg * 8;
            bah[p] = *reinterpret_cast<const short8*>(&xhi[off]);
            bal[p] = *reinterpret_cast<const short8*>(&xlo[off]);
        }
        size_t noff = (size_t)(icc < 5 ? icc + 1 : 5) * ICC_STRIDE;
        #pragma unroll
        for (int q = 0; q < NQ; ++q)
            nxt[q] = *reinterpret_cast<const short8*>(wrhi + noff + wbase[q]);
        #pragma unroll
        for (int h = 0; h < HN; ++h)
        #pragma unroll
        for (int j = 0; j < 3; ++j)
        #pragma unroll
        for (int p = 0; p < 4; ++p)
            a2[j][h][p] = __builtin_amdgcn_mfma_f32_16x16x32_bf16(
                cur[h * 3 + j], bah[p], a2[j][h][p], 0, 0, 0);
        #pragma unroll
        for (int h = 0; h < HN; ++h)
        #pragma unroll
        for (int j = 0; j < 3; ++j)
        #pragma unroll
        for (int p = 0; p < 4; ++p)
            a2[j][h][p] = __builtin_amdgcn_mfma_f32_16x16x32_bf16(
                lo6[h * 3 + j], bah[p], a2[j][h][p], 0, 0, 0);
        #pragma unroll
        for (int h = 0; h < HN; ++h)
        #pragma unroll
        for (int j = 0; j < 3; ++j)
        #pragma unroll
        for (int p = 0; p < 4; ++p)
            a2[j][h][p] = __builtin_amdgcn_mfma_f32_16x16x32_bf16(
                cur[h * 3 + j], bal[p], a2[j][h][p], 0, 0, 0);
    };

    #pragma unroll
    for (int ih = 0; ih < 3; ++ih) {
        r1step(2 * ih,     rA, rB);
        r1step(2 * ih + 1, rB, rA);
    }

    // ---- epilogue ----
    #pragma unroll
    for (int p = 0; p < 4; ++p) {
        const int tt = (wn * 4 + p) * 16 + col;
        const int t  = t0 + tt;
        const float mv = mask[(size_t)b * T + t];
        #pragma unroll
        for (int j = 0; j < 3; ++j) {
            const int ch = (wm * 3 + j) * 16 + sg * 4;
            float* op = o + ((size_t)b * C + ch) * T + t;
            if constexpr (LAST) {
                #pragma unroll
                for (int i = 0; i < 4; ++i)
                    op[(size_t)i * T] = (op[(size_t)i * T] + a2[j][0][p][i]) * mv;
            } else {
                short4v h4, l4;
                #pragma unroll
                for (int i = 0; i < 4; ++i) {
                    float nx = (xres[j][p][i] + a2[j][0][p][i]) * mv;
                    short h = f2bf(nx);
                    h4[i] = h;
                    l4[i] = f2bf(nx - bf2f(h));
                }
                size_t off = (size_t)b * T * C + (size_t)t * C + ch;
                *reinterpret_cast<short4v*>(xhout + off) = h4;
                *reinterpret_cast<short4v*>(xlout + off) = l4;
                #pragma unroll
                for (int i = 0; i < 4; ++i) {
                    if constexpr (FIRST) op[(size_t)i * T] = a2[j][1][p][i];
                    else                 op[(size_t)i * T] += a2[j][1][p][i];
                }
            }
        }
    }
}

#define WIN_STRIDE ((size_t)5 * 24 * 6 * 64 * 8)
#define WRS_STRIDE ((size_t)24 * 6 * 64 * 8)

extern "C" void kernel_launch(void* const* d_in, const int* in_sizes, int n_in,
                              void* d_out, int out_size, void* d_ws, size_t ws_size,
                              hipStream_t stream)
{
    const float* x      = (const float*)d_in[0];
    const float* mask   = (const float*)d_in[1];
    const float* W_in   = (const float*)d_in[2];
    const float* b_in   = (const float*)d_in[3];
    const float* W_rs   = (const float*)d_in[4];
    const float* b_rs   = (const float*)d_in[5];
    const float* W_last = (const float*)d_in[6];
    const float* b_last = (const float*)d_in[7];
    float* o = (float*)d_out;

    const size_t WIN_N = (size_t)L * WIN_STRIDE;
    const size_t WRS_N = (size_t)(L - 1) * WRS_STRIDE;
    const size_t WL_N  = (size_t)12 * 6 * 64 * 8;
    const size_t P     = (size_t)BATCH * T * C;      // plane elems (shorts)
    short* wchi = (short*)d_ws;
    short* wclo = wchi + WIN_N;
    short* wrhi = wclo + WIN_N;
    short* wrlo = wrhi + WRS_N;
    short* wlhi = wrlo + WRS_N;
    short* wllo = wlhi + WL_N;
    short* xah  = wllo + WL_N;
    short* xal  = xah + P;
    short* xbh  = xal + P;
    short* xbl  = xbh + P;

    {
        int tw = (int)(L * 5 * 24 * 6 * 64);
        fmt_win<<<(tw + 255) / 256, 256, 0, stream>>>(W_in, wchi, wclo, tw);
        int tr = (int)((L - 1) * 24 * 6 * 64);
        fmt_w11<<<(tr + 255) / 256, 256, 0, stream>>>(W_rs, wrhi, wrlo, 24, tr);
        int tl = (int)(12 * 6 * 64);
        fmt_w11<<<(tl + 255) / 256, 256, 0, stream>>>(W_last, wlhi, wllo, 12, tl);
        xpose<<<dim3(T / 64, BATCH), 256, 0, stream>>>(x, xah, xal);
    }

    (void)hipFuncSetAttribute(reinterpret_cast<const void*>(&wnet_layer<true, false>),
                              hipFuncAttributeMaxDynamicSharedMemorySize, SMEM_BYTES);
    (void)hipFuncSetAttribute(reinterpret_cast<const void*>(&wnet_layer<false, false>),
                              hipFuncAttributeMaxDynamicSharedMemorySize, SMEM_BYTES);
    (void)hipFuncSetAttribute(reinterpret_cast<const void*>(&wnet_layer<false, true>),
                              hipFuncAttributeMaxDynamicSharedMemorySize, SMEM_BYTES);

    dim3 grid(T / NT, BATCH);
    dim3 block(512);

    short* curh = xah; short* curl = xal;
    short* nxth = xbh; short* nxtl = xbl;

    wnet_layer<true, false><<<grid, block, SMEM_BYTES, stream>>>(
        curh, curl, nxth, nxtl, mask,
        wchi, wclo, b_in, wrhi, wrlo, b_rs, o);
    { short* t1 = curh; curh = nxth; nxth = t1;
      short* t2 = curl; curl = nxtl; nxtl = t2; }

    for (int i = 1; i < L - 1; ++i) {
        wnet_layer<false, false><<<grid, block, SMEM_BYTES, stream>>>(
            curh, curl, nxth, nxtl, mask,
            wchi + (size_t)i * WIN_STRIDE, wclo + (size_t)i * WIN_STRIDE,
            b_in + (size_t)i * 2 * C,
            wrhi + (size_t)i * WRS_STRIDE, wrlo + (size_t)i * WRS_STRIDE,
            b_rs + (size_t)i * 2 * C, o);
        { short* t1 = curh; curh = nxth; nxth = t1;
          short* t2 = curl; curl = nxtl; nxtl = t2; }
    }

    wnet_layer<false, true><<<grid, block, SMEM_BYTES, stream>>>(
        curh, curl, nullptr, nullptr, mask,
        wchi + (size_t)(L - 1) * WIN_STRIDE, wclo + (size_t)(L - 1) * WIN_STRIDE,
        b_in + (size_t)(L - 1) * 2 * C,
        wlhi, wllo, b_last, o);
}

// Round 9
// 2859.650 us; speedup vs baseline: 1.1795x; 1.0243x over previous
//
#include <hip/hip_runtime.h>
#include <hip/hip_bf16.h>

#define C 192
#define T 4096
#define L 16
#define BATCH 16
#define NT 128         // t-positions per block
#define XR 136         // x tile rows incl. halo 4+4
#define CPAD 200       // padded channel stride in LDS (shorts) -> 400B rows
#define SMEM_BYTES (2 * XR * CPAD * 2)   // xhi + xlo: 108,800 B

#define CONV_TAP_STRIDE 73728   // elems: 24*6*512
#define MT_STRIDE       3072    // 6*512
#define ICC_STRIDE      512

typedef __attribute__((ext_vector_type(8))) short short8;
typedef __attribute__((ext_vector_type(4))) short short4v;
typedef __attribute__((ext_vector_type(4))) float f32x4;

__device__ __forceinline__ short f2bf(float v) {
    __hip_bfloat16 h = __float2bfloat16(v);
    return *reinterpret_cast<const short*>(&h);
}
__device__ __forceinline__ float bf2f(short s) {
    unsigned u = ((unsigned)(unsigned short)s) << 16;
    float f;
    __builtin_memcpy(&f, &u, 4);
    return f;
}

__device__ __forceinline__ float gatefn(float x1, float x2) {
    float ax = fabsf(x1);
    float e  = __expf(-2.f * ax);
    float th = __builtin_copysignf((1.f - e) / (1.f + e), x1);
    float sg = 1.f / (1.f + __expf(-x2));
    return th * sg;
}

// ---- weight pre-format with hi/lo bf16 split (Dekker: v-hi exact in fp32) ----
__global__ __launch_bounds__(256)
void fmt_win(const float* __restrict__ W, short* __restrict__ dhi,
             short* __restrict__ dlo, int total) {
    int gid = blockIdx.x * 256 + threadIdx.x;
    if (gid >= total) return;
    int lane = gid & 63; int r = gid >> 6;
    int icc = r % 6; r /= 6;
    int mt  = r % 24; r /= 24;
    int tap = r % 5;  int l = r / 5;
    int oc  = mt * 16 + (lane & 15);
    int ic0 = icc * 32 + (lane >> 4) * 8;
    const float* s = W + ((size_t)((l * 384 + oc) * 192 + ic0)) * 5 + tap;
    short8 vh, vl;
    #pragma unroll
    for (int i = 0; i < 8; ++i) {
        float v = s[(size_t)i * 5];
        short h = f2bf(v);
        vh[i] = h;
        vl[i] = f2bf(v - bf2f(h));
    }
    *reinterpret_cast<short8*>(dhi + (size_t)gid * 8) = vh;
    *reinterpret_cast<short8*>(dlo + (size_t)gid * 8) = vl;
}

__global__ __launch_bounds__(256)
void fmt_w11(const float* __restrict__ W, short* __restrict__ dhi,
             short* __restrict__ dlo, int mtc, int total) {
    int gid = blockIdx.x * 256 + threadIdx.x;
    if (gid >= total) return;
    int lane = gid & 63; int r = gid >> 6;
    int icc = r % 6; r /= 6;
    int mt  = r % mtc; int l = r / mtc;
    int oc  = mt * 16 + (lane & 15);
    int ic0 = icc * 32 + (lane >> 4) * 8;
    const float* s = W + (size_t)(l * (mtc * 16) + oc) * 192 + ic0;
    short8 vh, vl;
    #pragma unroll
    for (int i = 0; i < 8; ++i) {
        float v = s[i];
        short h = f2bf(v);
        vh[i] = h;
        vl[i] = f2bf(v - bf2f(h));
    }
    *reinterpret_cast<short8*>(dhi + (size_t)gid * 8) = vh;
    *reinterpret_cast<short8*>(dlo + (size_t)gid * 8) = vl;
}

// ---- one-time transpose+split: x fp32 [b][c][t] -> hi/lo bf16 planes [b][t][c] ----
__global__ __launch_bounds__(256)
void xpose(const float* __restrict__ x, short* __restrict__ xh, short* __restrict__ xl)
{
    __shared__ float tile[C][65];
    const int t0 = blockIdx.x * 64;
    const int b  = blockIdx.y;
    const float* xg = x + (size_t)b * C * T;
    for (int idx = threadIdx.x; idx < C * 16; idx += 256) {
        int ch = idx & 15, c = idx >> 4;
        f32x4 v = *reinterpret_cast<const f32x4*>(xg + (size_t)c * T + t0 + ch * 4);
        #pragma unroll
        for (int q = 0; q < 4; ++q) tile[c][ch * 4 + q] = v[q];
    }
    __syncthreads();
    for (int idx = threadIdx.x; idx < 64 * 24; idx += 256) {
        int cc = idx % 24, t = idx / 24;
        short8 h8, l8;
        #pragma unroll
        for (int i = 0; i < 8; ++i) {
            float v = tile[cc * 8 + i][t];
            short h = f2bf(v);
            h8[i] = h;
            l8[i] = f2bf(v - bf2f(h));
        }
        size_t off = (size_t)b * T * C + (size_t)(t0 + t) * C + cc * 8;
        *reinterpret_cast<short8*>(xh + off) = h8;
        *reinterpret_cast<short8*>(xl + off) = l8;
    }
}

// ---- fused WaveNet layer: x master is hi/lo bf16 [b][t][c] planes in ws ----
// 8 waves: wm=wid&3 (3 mt-pairs), wn=wid>>2 (4 nt-subtiles each)
// Full 1-step-lookahead weight pipeline (hi AND lo double-buffered).
// amdgpu_waves_per_eu(2,2): LDS caps us at 2 waves/EU anyway; pin it so the
// register allocator uses the 256-VGPR budget instead of compiling the
// pipeline away (r8: VGPR=128, prefetch sunk to use points).
template<bool FIRST, bool LAST>
__global__
__attribute__((amdgpu_flat_work_group_size(512, 512), amdgpu_waves_per_eu(2, 2)))
void wnet_layer(const short* __restrict__ xhin, const short* __restrict__ xlin,
                short* __restrict__ xhout, short* __restrict__ xlout,
                const float* __restrict__ mask,
                const short* __restrict__ wchi, const short* __restrict__ wclo,
                const float* __restrict__ bc,
                const short* __restrict__ wrhi, const short* __restrict__ wrlo,
                const float* __restrict__ br,
                float* __restrict__ o)
{
    extern __shared__ __align__(16) char smem_raw[];
    short* xhi = reinterpret_cast<short*>(smem_raw);
    short* xlo = xhi + XR * CPAD;

    const int tid = threadIdx.x;
    const int t0  = blockIdx.x * NT;
    const int b   = blockIdx.y;

    // ---- stage: pure 16B vector copies ----
    {
        const short* gh = xhin + (size_t)b * T * C;
        const short* gl = xlin + (size_t)b * T * C;
        for (int idx = tid; idx < 2 * XR * 24; idx += 512) {
            int chunk = idx % 24;
            int r     = (idx / 24) % XR;
            int plane = idx / (24 * XR);
            int t = t0 - 4 + r;
            short8 v = {};
            if (t >= 0 && t < T)
                v = *reinterpret_cast<const short8*>(
                        (plane ? gl : gh) + (size_t)t * C + chunk * 8);
            *reinterpret_cast<short8*>((plane ? xlo : xhi) + r * CPAD + chunk * 8) = v;
        }
    }
    __syncthreads();

    const int lane = tid & 63;
    const int wid  = tid >> 6;
    const int wm   = wid & 3;
    const int wn   = wid >> 2;      // 0..1
    const int col  = lane & 15;
    const int sg   = lane >> 4;

    // per-(h*3+j) weight element offsets (sans tap/icc)
    int wbase[6];
    #pragma unroll
    for (int q = 0; q < 6; ++q) {
        int h = q / 3, j = q % 3;
        int mt = h * 12 + wm * 3 + j;
        wbase[q] = mt * MT_STRIDE + lane * 8;
    }

    // ---- conv K5, 3-pass Dekker split, full-lookahead pipeline ----
    f32x4 acc[3][2][4];
    #pragma unroll
    for (int j = 0; j < 3; ++j)
    #pragma unroll
    for (int h = 0; h < 2; ++h) {
        f32x4 bv = *reinterpret_cast<const f32x4*>(bc + (h * 12 + wm * 3 + j) * 16 + sg * 4);
        #pragma unroll
        for (int p = 0; p < 4; ++p) acc[j][h][p] = bv;
    }

    short8 hA[6], lA[6], hB[6], lB[6];
    #pragma unroll
    for (int q = 0; q < 6; ++q) {
        hA[q] = *reinterpret_cast<const short8*>(wchi + wbase[q]);   // (tap0,icc0)
        lA[q] = *reinterpret_cast<const short8*>(wclo + wbase[q]);
    }

    auto convstep = [&](int icc, short8 (&curH)[6], short8 (&curL)[6],
                        short8 (&nxtH)[6], short8 (&nxtL)[6],
                        size_t tapoff, size_t ntapoff, int tap) {
        // 1. issue next step's hi+lo weight loads (covered by this step's MFMAs)
        size_t noff = (icc == 5) ? ntapoff : tapoff + (size_t)(icc + 1) * ICC_STRIDE;
        #pragma unroll
        for (int q = 0; q < 6; ++q) {
            nxtH[q] = *reinterpret_cast<const short8*>(wchi + noff + wbase[q]);
            nxtL[q] = *reinterpret_cast<const short8*>(wclo + noff + wbase[q]);
        }
        // 2. b-frags (LDS)
        short8 bh[4], bl[4];
        #pragma unroll
        for (int p = 0; p < 4; ++p) {
            int off = ((wn * 4 + p) * 16 + col + tap + 2) * CPAD + icc * 32 + sg * 8;
            bh[p] = *reinterpret_cast<const short8*>(&xhi[off]);
            bl[p] = *reinterpret_cast<const short8*>(&xlo[off]);
        }
        // 3. three MFMA passes on current (register-resident) weights
        #pragma unroll
        for (int h = 0; h < 2; ++h)
        #pragma unroll
        for (int j = 0; j < 3; ++j)
        #pragma unroll
        for (int p = 0; p < 4; ++p)
            acc[j][h][p] = __builtin_amdgcn_mfma_f32_16x16x32_bf16(
                curH[h * 3 + j], bh[p], acc[j][h][p], 0, 0, 0);
        #pragma unroll
        for (int h = 0; h < 2; ++h)
        #pragma unroll
        for (int j = 0; j < 3; ++j)
        #pragma unroll
        for (int p = 0; p < 4; ++p)
            acc[j][h][p] = __builtin_amdgcn_mfma_f32_16x16x32_bf16(
                curL[h * 3 + j], bh[p], acc[j][h][p], 0, 0, 0);
        #pragma unroll
        for (int h = 0; h < 2; ++h)
        #pragma unroll
        for (int j = 0; j < 3; ++j)
        #pragma unroll
        for (int p = 0; p < 4; ++p)
            acc[j][h][p] = __builtin_amdgcn_mfma_f32_16x16x32_bf16(
                curH[h * 3 + j], bl[p], acc[j][h][p], 0, 0, 0);
    };

    for (int tap = 0; tap < 5; ++tap) {
        const size_t tapoff  = (size_t)tap * CONV_TAP_STRIDE;
        const size_t ntapoff = (size_t)(tap < 4 ? tap + 1 : 4) * CONV_TAP_STRIDE;
        #pragma unroll
        for (int ih = 0; ih < 3; ++ih) {
            convstep(2 * ih,     hA, lA, hB, lB, tapoff, ntapoff, tap);
            convstep(2 * ih + 1, hB, lB, hA, lA, tapoff, ntapoff, tap);
        }
    }

    // ---- residual x pre-read from LDS (before acts overwrite) ----
    float xres[3][4][4];
    if constexpr (!LAST) {
        #pragma unroll
        for (int p = 0; p < 4; ++p) {
            const int row = (wn * 4 + p) * 16 + col + 4;
            #pragma unroll
            for (int j = 0; j < 3; ++j) {
                const int ch = (wm * 3 + j) * 16 + sg * 4;
                short4v h4 = *reinterpret_cast<const short4v*>(&xhi[row * CPAD + ch]);
                short4v l4 = *reinterpret_cast<const short4v*>(&xlo[row * CPAD + ch]);
                #pragma unroll
                for (int i = 0; i < 4; ++i) xres[j][p][i] = bf2f(h4[i]) + bf2f(l4[i]);
            }
        }
    }
    __syncthreads();   // conv + residual LDS reads done before acts overwrite

    // ---- gate -> acts hi/lo (reuse xhi/xlo, rows [0,NT)) ----
    #pragma unroll
    for (int j = 0; j < 3; ++j)
    #pragma unroll
    for (int p = 0; p < 4; ++p) {
        const int tt = (wn * 4 + p) * 16 + col;
        const int ch = (wm * 3 + j) * 16 + sg * 4;
        float av[4];
        #pragma unroll
        for (int i = 0; i < 4; ++i)
            av[i] = gatefn(acc[j][0][p][i], acc[j][1][p][i]);
        #pragma unroll
        for (int i2 = 0; i2 < 2; ++i2) {
            short h0 = f2bf(av[i2 * 2]);
            short h1 = f2bf(av[i2 * 2 + 1]);
            short l0 = f2bf(av[i2 * 2]     - bf2f(h0));
            short l1 = f2bf(av[i2 * 2 + 1] - bf2f(h1));
            unsigned ph = (unsigned)(unsigned short)h0 | ((unsigned)(unsigned short)h1 << 16);
            unsigned pl = (unsigned)(unsigned short)l0 | ((unsigned)(unsigned short)l1 << 16);
            *reinterpret_cast<unsigned*>(&xhi[tt * CPAD + ch + i2 * 2]) = ph;
            *reinterpret_cast<unsigned*>(&xlo[tt * CPAD + ch + i2 * 2]) = pl;
        }
    }
    __syncthreads();

    // ---- 1x1 (3-pass split), full-lookahead pipeline over 6 icc steps ----
    constexpr int HN = LAST ? 1 : 2;
    constexpr int NQ = HN * 3;
    f32x4 a2[3][HN][4];
    #pragma unroll
    for (int j = 0; j < 3; ++j)
    #pragma unroll
    for (int h = 0; h < HN; ++h) {
        f32x4 bv = *reinterpret_cast<const f32x4*>(br + (h * 12 + wm * 3 + j) * 16 + sg * 4);
        #pragma unroll
        for (int p = 0; p < 4; ++p) a2[j][h][p] = bv;
    }

    short8 rHA[NQ], rLA[NQ], rHB[NQ], rLB[NQ];
    #pragma unroll
    for (int q = 0; q < NQ; ++q) {
        rHA[q] = *reinterpret_cast<const short8*>(wrhi + wbase[q]);   // icc=0
        rLA[q] = *reinterpret_cast<const short8*>(wrlo + wbase[q]);
    }

    auto r1step = [&](int icc, short8 (&curH)[NQ], short8 (&curL)[NQ],
                      short8 (&nxtH)[NQ], short8 (&nxtL)[NQ]) {
        size_t noff = (size_t)(icc < 5 ? icc + 1 : 5) * ICC_STRIDE;
        #pragma unroll
        for (int q = 0; q < NQ; ++q) {
            nxtH[q] = *reinterpret_cast<const short8*>(wrhi + noff + wbase[q]);
            nxtL[q] = *reinterpret_cast<const short8*>(wrlo + noff + wbase[q]);
        }
        short8 bah[4], bal[4];
        #pragma unroll
        for (int p = 0; p < 4; ++p) {
            int off = ((wn * 4 + p) * 16 + col) * CPAD + icc * 32 + sg * 8;
            bah[p] = *reinterpret_cast<const short8*>(&xhi[off]);
            bal[p] = *reinterpret_cast<const short8*>(&xlo[off]);
        }
        #pragma unroll
        for (int h = 0; h < HN; ++h)
        #pragma unroll
        for (int j = 0; j < 3; ++j)
        #pragma unroll
        for (int p = 0; p < 4; ++p)
            a2[j][h][p] = __builtin_amdgcn_mfma_f32_16x16x32_bf16(
                curH[h * 3 + j], bah[p], a2[j][h][p], 0, 0, 0);
        #pragma unroll
        for (int h = 0; h < HN; ++h)
        #pragma unroll
        for (int j = 0; j < 3; ++j)
        #pragma unroll
        for (int p = 0; p < 4; ++p)
            a2[j][h][p] = __builtin_amdgcn_mfma_f32_16x16x32_bf16(
                curL[h * 3 + j], bah[p], a2[j][h][p], 0, 0, 0);
        #pragma unroll
        for (int h = 0; h < HN; ++h)
        #pragma unroll
        for (int j = 0; j < 3; ++j)
        #pragma unroll
        for (int p = 0; p < 4; ++p)
            a2[j][h][p] = __builtin_amdgcn_mfma_f32_16x16x32_bf16(
                curH[h * 3 + j], bal[p], a2[j][h][p], 0, 0, 0);
    };

    #pragma unroll
    for (int ih = 0; ih < 3; ++ih) {
        r1step(2 * ih,     rHA, rLA, rHB, rLB);
        r1step(2 * ih + 1, rHB, rLB, rHA, rLA);
    }

    // ---- epilogue ----
    #pragma unroll
    for (int p = 0; p < 4; ++p) {
        const int tt = (wn * 4 + p) * 16 + col;
        const int t  = t0 + tt;
        const float mv = mask[(size_t)b * T + t];
        #pragma unroll
        for (int j = 0; j < 3; ++j) {
            const int ch = (wm * 3 + j) * 16 + sg * 4;
            float* op = o + ((size_t)b * C + ch) * T + t;
            if constexpr (LAST) {
                #pragma unroll
                for (int i = 0; i < 4; ++i)
                    op[(size_t)i * T] = (op[(size_t)i * T] + a2[j][0][p][i]) * mv;
            } else {
                short4v h4, l4;
                #pragma unroll
                for (int i = 0; i < 4; ++i) {
                    float nx = (xres[j][p][i] + a2[j][0][p][i]) * mv;
                    short h = f2bf(nx);
                    h4[i] = h;
                    l4[i] = f2bf(nx - bf2f(h));
                }
                size_t off = (size_t)b * T * C + (size_t)t * C + ch;
                *reinterpret_cast<short4v*>(xhout + off) = h4;
                *reinterpret_cast<short4v*>(xlout + off) = l4;
                #pragma unroll
                for (int i = 0; i < 4; ++i) {
                    if constexpr (FIRST) op[(size_t)i * T] = a2[j][1][p][i];
                    else                 op[(size_t)i * T] += a2[j][1][p][i];
                }
            }
        }
    }
}

#define WIN_STRIDE ((size_t)5 * 24 * 6 * 64 * 8)
#define WRS_STRIDE ((size_t)24 * 6 * 64 * 8)

extern "C" void kernel_launch(void* const* d_in, const int* in_sizes, int n_in,
                              void* d_out, int out_size, void* d_ws, size_t ws_size,
                              hipStream_t stream)
{
    const float* x      = (const float*)d_in[0];
    const float* mask   = (const float*)d_in[1];
    const float* W_in   = (const float*)d_in[2];
    const float* b_in   = (const float*)d_in[3];
    const float* W_rs   = (const float*)d_in[4];
    const float* b_rs   = (const float*)d_in[5];
    const float* W_last = (const float*)d_in[6];
    const float* b_last = (const float*)d_in[7];
    float* o = (float*)d_out;

    const size_t WIN_N = (size_t)L * WIN_STRIDE;
    const size_t WRS_N = (size_t)(L - 1) * WRS_STRIDE;
    const size_t WL_N  = (size_t)12 * 6 * 64 * 8;
    const size_t P     = (size_t)BATCH * T * C;      // plane elems (shorts)
    short* wchi = (short*)d_ws;
    short* wclo = wchi + WIN_N;
    short* wrhi = wclo + WIN_N;
    short* wrlo = wrhi + WRS_N;
    short* wlhi = wrlo + WRS_N;
    short* wllo = wlhi + WL_N;
    short* xah  = wllo + WL_N;
    short* xal  = xah + P;
    short* xbh  = xal + P;
    short* xbl  = xbh + P;

    {
        int tw = (int)(L * 5 * 24 * 6 * 64);
        fmt_win<<<(tw + 255) / 256, 256, 0, stream>>>(W_in, wchi, wclo, tw);
        int tr = (int)((L - 1) * 24 * 6 * 64);
        fmt_w11<<<(tr + 255) / 256, 256, 0, stream>>>(W_rs, wrhi, wrlo, 24, tr);
        int tl = (int)(12 * 6 * 64);
        fmt_w11<<<(tl + 255) / 256, 256, 0, stream>>>(W_last, wlhi, wllo, 12, tl);
        xpose<<<dim3(T / 64, BATCH), 256, 0, stream>>>(x, xah, xal);
    }

    (void)hipFuncSetAttribute(reinterpret_cast<const void*>(&wnet_layer<true, false>),
                              hipFuncAttributeMaxDynamicSharedMemorySize, SMEM_BYTES);
    (void)hipFuncSetAttribute(reinterpret_cast<const void*>(&wnet_layer<false, false>),
                              hipFuncAttributeMaxDynamicSharedMemorySize, SMEM_BYTES);
    (void)hipFuncSetAttribute(reinterpret_cast<const void*>(&wnet_layer<false, true>),
                              hipFuncAttributeMaxDynamicSharedMemorySize, SMEM_BYTES);

    dim3 grid(T / NT, BATCH);
    dim3 block(512);

    short* curh = xah; short* curl = xal;
    short* nxth = xbh; short* nxtl = xbl;

    wnet_layer<true, false><<<grid, block, SMEM_BYTES, stream>>>(
        curh, curl, nxth, nxtl, mask,
        wchi, wclo, b_in, wrhi, wrlo, b_rs, o);
    { short* t1 = curh; curh = nxth; nxth = t1;
      short* t2 = curl; curl = nxtl; nxtl = t2; }

    for (int i = 1; i < L - 1; ++i) {
        wnet_layer<false, false><<<grid, block, SMEM_BYTES, stream>>>(
            curh, curl, nxth, nxtl, mask,
            wchi + (size_t)i * WIN_STRIDE, wclo + (size_t)i * WIN_STRIDE,
            b_in + (size_t)i * 2 * C,
            wrhi + (size_t)i * WRS_STRIDE, wrlo + (size_t)i * WRS_STRIDE,
            b_rs + (size_t)i * 2 * C, o);
        { short* t1 = curh; curh = nxth; nxth = t1;
          short* t2 = curl; curl = nxtl; nxtl = t2; }
    }

    wnet_layer<false, true><<<grid, block, SMEM_BYTES, stream>>>(
        curh, curl, nullptr, nullptr, mask,
        wchi + (size_t)(L - 1) * WIN_STRIDE, wclo + (size_t)(L - 1) * WIN_STRIDE,
        b_in + (size_t)(L - 1) * 2 * C,
        wlhi, wllo, b_last, o);
}

// Round 10
// 2630.856 us; speedup vs baseline: 1.2820x; 1.0870x over previous
//
#include <hip/hip_runtime.h>
#include <hip/hip_bf16.h>

#define C 192
#define T 4096
#define L 16
#define BATCH 16
#define NT 128         // t-positions per block
#define XR 136         // x tile rows incl. halo 4+4
#define CPAD 200       // padded channel stride in LDS (shorts) -> 400B rows
#define SMEM_BYTES (2 * XR * CPAD * 2)   // xhi + xlo: 108,800 B

#define CONV_TAP_STRIDE 73728   // elems: 24*6*512
#define MT_STRIDE       3072    // 6*512
#define ICC_STRIDE      512

typedef __attribute__((ext_vector_type(8))) short short8;
typedef __attribute__((ext_vector_type(4))) short short4v;
typedef __attribute__((ext_vector_type(4))) float f32x4;

__device__ __forceinline__ short f2bf(float v) {
    __hip_bfloat16 h = __float2bfloat16(v);
    return *reinterpret_cast<const short*>(&h);
}
__device__ __forceinline__ float bf2f(short s) {
    unsigned u = ((unsigned)(unsigned short)s) << 16;
    float f;
    __builtin_memcpy(&f, &u, 4);
    return f;
}

__device__ __forceinline__ float gatefn(float x1, float x2) {
    float ax = fabsf(x1);
    float e  = __expf(-2.f * ax);
    float th = __builtin_copysignf((1.f - e) / (1.f + e), x1);
    float sg = 1.f / (1.f + __expf(-x2));
    return th * sg;
}

// ---- weight pre-format with hi/lo bf16 split (Dekker: v-hi exact in fp32) ----
__global__ __launch_bounds__(256)
void fmt_win(const float* __restrict__ W, short* __restrict__ dhi,
             short* __restrict__ dlo, int total) {
    int gid = blockIdx.x * 256 + threadIdx.x;
    if (gid >= total) return;
    int lane = gid & 63; int r = gid >> 6;
    int icc = r % 6; r /= 6;
    int mt  = r % 24; r /= 24;
    int tap = r % 5;  int l = r / 5;
    int oc  = mt * 16 + (lane & 15);
    int ic0 = icc * 32 + (lane >> 4) * 8;
    const float* s = W + ((size_t)((l * 384 + oc) * 192 + ic0)) * 5 + tap;
    short8 vh, vl;
    #pragma unroll
    for (int i = 0; i < 8; ++i) {
        float v = s[(size_t)i * 5];
        short h = f2bf(v);
        vh[i] = h;
        vl[i] = f2bf(v - bf2f(h));
    }
    *reinterpret_cast<short8*>(dhi + (size_t)gid * 8) = vh;
    *reinterpret_cast<short8*>(dlo + (size_t)gid * 8) = vl;
}

__global__ __launch_bounds__(256)
void fmt_w11(const float* __restrict__ W, short* __restrict__ dhi,
             short* __restrict__ dlo, int mtc, int total) {
    int gid = blockIdx.x * 256 + threadIdx.x;
    if (gid >= total) return;
    int lane = gid & 63; int r = gid >> 6;
    int icc = r % 6; r /= 6;
    int mt  = r % mtc; int l = r / mtc;
    int oc  = mt * 16 + (lane & 15);
    int ic0 = icc * 32 + (lane >> 4) * 8;
    const float* s = W + (size_t)(l * (mtc * 16) + oc) * 192 + ic0;
    short8 vh, vl;
    #pragma unroll
    for (int i = 0; i < 8; ++i) {
        float v = s[i];
        short h = f2bf(v);
        vh[i] = h;
        vl[i] = f2bf(v - bf2f(h));
    }
    *reinterpret_cast<short8*>(dhi + (size_t)gid * 8) = vh;
    *reinterpret_cast<short8*>(dlo + (size_t)gid * 8) = vl;
}

// ---- one-time transpose+split: x fp32 [b][c][t] -> hi/lo bf16 planes [b][t][c] ----
__global__ __launch_bounds__(256)
void xpose(const float* __restrict__ x, short* __restrict__ xh, short* __restrict__ xl)
{
    __shared__ float tile[C][65];
    const int t0 = blockIdx.x * 64;
    const int b  = blockIdx.y;
    const float* xg = x + (size_t)b * C * T;
    for (int idx = threadIdx.x; idx < C * 16; idx += 256) {
        int ch = idx & 15, c = idx >> 4;
        f32x4 v = *reinterpret_cast<const f32x4*>(xg + (size_t)c * T + t0 + ch * 4);
        #pragma unroll
        for (int q = 0; q < 4; ++q) tile[c][ch * 4 + q] = v[q];
    }
    __syncthreads();
    for (int idx = threadIdx.x; idx < 64 * 24; idx += 256) {
        int cc = idx % 24, t = idx / 24;
        short8 h8, l8;
        #pragma unroll
        for (int i = 0; i < 8; ++i) {
            float v = tile[cc * 8 + i][t];
            short h = f2bf(v);
            h8[i] = h;
            l8[i] = f2bf(v - bf2f(h));
        }
        size_t off = (size_t)b * T * C + (size_t)(t0 + t) * C + cc * 8;
        *reinterpret_cast<short8*>(xh + off) = h8;
        *reinterpret_cast<short8*>(xl + off) = l8;
    }
}

// ---- fused WaveNet layer: x master is hi/lo bf16 [b][t][c] planes in ws ----
// 8 waves: wm=wid&3 (3 mt-pairs), wn=wid>>2 (4 nt-subtiles each)
// Per step: {lo-demand loads, next-hi prefetch, ds_reads} | sched_barrier(0) | MFMAs
// so the machine scheduler cannot sink the prefetch (r8/r9: VGPR=124 => pipeline
// was compiled away). 1x1 split into two h-phases to cap peak VGPR pressure.
template<bool FIRST, bool LAST>
__global__
__attribute__((amdgpu_flat_work_group_size(512, 512), amdgpu_waves_per_eu(2, 2)))
void wnet_layer(const short* __restrict__ xhin, const short* __restrict__ xlin,
                short* __restrict__ xhout, short* __restrict__ xlout,
                const float* __restrict__ mask,
                const short* __restrict__ wchi, const short* __restrict__ wclo,
                const float* __restrict__ bc,
                const short* __restrict__ wrhi, const short* __restrict__ wrlo,
                const float* __restrict__ br,
                float* __restrict__ o)
{
    extern __shared__ __align__(16) char smem_raw[];
    short* xhi = reinterpret_cast<short*>(smem_raw);
    short* xlo = xhi + XR * CPAD;

    const int tid = threadIdx.x;
    const int t0  = blockIdx.x * NT;
    const int b   = blockIdx.y;

    // ---- stage: pure 16B vector copies ----
    {
        const short* gh = xhin + (size_t)b * T * C;
        const short* gl = xlin + (size_t)b * T * C;
        for (int idx = tid; idx < 2 * XR * 24; idx += 512) {
            int chunk = idx % 24;
            int r     = (idx / 24) % XR;
            int plane = idx / (24 * XR);
            int t = t0 - 4 + r;
            short8 v = {};
            if (t >= 0 && t < T)
                v = *reinterpret_cast<const short8*>(
                        (plane ? gl : gh) + (size_t)t * C + chunk * 8);
            *reinterpret_cast<short8*>((plane ? xlo : xhi) + r * CPAD + chunk * 8) = v;
        }
    }
    __syncthreads();

    const int lane = tid & 63;
    const int wid  = tid >> 6;
    const int wm   = wid & 3;
    const int wn   = wid >> 2;      // 0..1
    const int col  = lane & 15;
    const int sg   = lane >> 4;

    // per-(h*3+j) weight element offsets (sans tap/icc)
    int wbase[6];
    #pragma unroll
    for (int q = 0; q < 6; ++q) {
        int h = q / 3, j = q % 3;
        int mt = h * 12 + wm * 3 + j;
        wbase[q] = mt * MT_STRIDE + lane * 8;
    }

    // ---- conv K5, 3-pass Dekker split, pinned pipeline ----
    f32x4 acc[3][2][4];
    #pragma unroll
    for (int j = 0; j < 3; ++j)
    #pragma unroll
    for (int h = 0; h < 2; ++h) {
        f32x4 bv = *reinterpret_cast<const f32x4*>(bc + (h * 12 + wm * 3 + j) * 16 + sg * 4);
        #pragma unroll
        for (int p = 0; p < 4; ++p) acc[j][h][p] = bv;
    }

    short8 hA[6], hB[6];
    #pragma unroll
    for (int q = 0; q < 6; ++q)
        hA[q] = *reinterpret_cast<const short8*>(wchi + wbase[q]);   // (tap0,icc0)

    auto convstep = [&](int icc, short8 (&curH)[6], short8 (&nxtH)[6],
                        size_t tapoff, size_t ntapoff, int tap) {
        // 1. demand lo for this step (tightest deadline: consumed in pass 2)
        short8 lo6[6];
        const size_t coff = tapoff + (size_t)icc * ICC_STRIDE;
        #pragma unroll
        for (int q = 0; q < 6; ++q)
            lo6[q] = *reinterpret_cast<const short8*>(wclo + coff + wbase[q]);
        // 2. prefetch next step's hi (deadline: next step's pass 1)
        const size_t noff = (icc == 5) ? ntapoff : coff + ICC_STRIDE;
        #pragma unroll
        for (int q = 0; q < 6; ++q)
            nxtH[q] = *reinterpret_cast<const short8*>(wchi + noff + wbase[q]);
        // 3. b-frags (LDS)
        short8 bh[4], bl[4];
        #pragma unroll
        for (int p = 0; p < 4; ++p) {
            int off = ((wn * 4 + p) * 16 + col + tap + 2) * CPAD + icc * 32 + sg * 8;
            bh[p] = *reinterpret_cast<const short8*>(&xhi[off]);
            bl[p] = *reinterpret_cast<const short8*>(&xlo[off]);
        }
        // pin: loads stay above, MFMAs below
        __builtin_amdgcn_sched_barrier(0);
        // pass 1: hi*hi (covers lo6's L2 latency)
        #pragma unroll
        for (int h = 0; h < 2; ++h)
        #pragma unroll
        for (int j = 0; j < 3; ++j)
        #pragma unroll
        for (int p = 0; p < 4; ++p)
            acc[j][h][p] = __builtin_amdgcn_mfma_f32_16x16x32_bf16(
                curH[h * 3 + j], bh[p], acc[j][h][p], 0, 0, 0);
        // pass 2: lo*hi
        #pragma unroll
        for (int h = 0; h < 2; ++h)
        #pragma unroll
        for (int j = 0; j < 3; ++j)
        #pragma unroll
        for (int p = 0; p < 4; ++p)
            acc[j][h][p] = __builtin_amdgcn_mfma_f32_16x16x32_bf16(
                lo6[h * 3 + j], bh[p], acc[j][h][p], 0, 0, 0);
        // pass 3: hi*lo
        #pragma unroll
        for (int h = 0; h < 2; ++h)
        #pragma unroll
        for (int j = 0; j < 3; ++j)
        #pragma unroll
        for (int p = 0; p < 4; ++p)
            acc[j][h][p] = __builtin_amdgcn_mfma_f32_16x16x32_bf16(
                curH[h * 3 + j], bl[p], acc[j][h][p], 0, 0, 0);
    };

    for (int tap = 0; tap < 5; ++tap) {
        const size_t tapoff  = (size_t)tap * CONV_TAP_STRIDE;
        const size_t ntapoff = (size_t)(tap < 4 ? tap + 1 : 4) * CONV_TAP_STRIDE;
        #pragma unroll
        for (int ih = 0; ih < 3; ++ih) {
            convstep(2 * ih,     hA, hB, tapoff, ntapoff, tap);
            convstep(2 * ih + 1, hB, hA, tapoff, ntapoff, tap);
        }
    }

    // ---- residual x pre-read from LDS (before acts overwrite) ----
    float xres[3][4][4];
    if constexpr (!LAST) {
        #pragma unroll
        for (int p = 0; p < 4; ++p) {
            const int row = (wn * 4 + p) * 16 + col + 4;
            #pragma unroll
            for (int j = 0; j < 3; ++j) {
                const int ch = (wm * 3 + j) * 16 + sg * 4;
                short4v h4 = *reinterpret_cast<const short4v*>(&xhi[row * CPAD + ch]);
                short4v l4 = *reinterpret_cast<const short4v*>(&xlo[row * CPAD + ch]);
                #pragma unroll
                for (int i = 0; i < 4; ++i) xres[j][p][i] = bf2f(h4[i]) + bf2f(l4[i]);
            }
        }
    }
    __syncthreads();   // conv + residual LDS reads done before acts overwrite

    // ---- gate -> acts hi/lo (reuse xhi/xlo, rows [0,NT)) ----
    #pragma unroll
    for (int j = 0; j < 3; ++j)
    #pragma unroll
    for (int p = 0; p < 4; ++p) {
        const int tt = (wn * 4 + p) * 16 + col;
        const int ch = (wm * 3 + j) * 16 + sg * 4;
        float av[4];
        #pragma unroll
        for (int i = 0; i < 4; ++i)
            av[i] = gatefn(acc[j][0][p][i], acc[j][1][p][i]);
        #pragma unroll
        for (int i2 = 0; i2 < 2; ++i2) {
            short h0 = f2bf(av[i2 * 2]);
            short h1 = f2bf(av[i2 * 2 + 1]);
            short l0 = f2bf(av[i2 * 2]     - bf2f(h0));
            short l1 = f2bf(av[i2 * 2 + 1] - bf2f(h1));
            unsigned ph = (unsigned)(unsigned short)h0 | ((unsigned)(unsigned short)h1 << 16);
            unsigned pl = (unsigned)(unsigned short)l0 | ((unsigned)(unsigned short)l1 << 16);
            *reinterpret_cast<unsigned*>(&xhi[tt * CPAD + ch + i2 * 2]) = ph;
            *reinterpret_cast<unsigned*>(&xlo[tt * CPAD + ch + i2 * 2]) = pl;
        }
    }
    __syncthreads();

    // ---- 1x1 (3-pass split), two sequential h-phases, pinned pipeline ----
    const float* mb = mask + (size_t)b * T;
    float mv[4];
    #pragma unroll
    for (int p = 0; p < 4; ++p) mv[p] = mb[t0 + (wn * 4 + p) * 16 + col];

    constexpr int HN = LAST ? 1 : 2;
    #pragma unroll
    for (int h = 0; h < HN; ++h) {
        f32x4 a2[3][4];
        #pragma unroll
        for (int j = 0; j < 3; ++j) {
            f32x4 bv = *reinterpret_cast<const f32x4*>(br + (h * 12 + wm * 3 + j) * 16 + sg * 4);
            #pragma unroll
            for (int p = 0; p < 4; ++p) a2[j][p] = bv;
        }
        const int* wb = wbase + h * 3;

        short8 rA[3], rB[3];
        #pragma unroll
        for (int q = 0; q < 3; ++q)
            rA[q] = *reinterpret_cast<const short8*>(wrhi + wb[q]);   // icc=0

        auto r1step = [&](int icc, short8 (&cur)[3], short8 (&nxt)[3]) {
            short8 lo3[3];
            const size_t coff = (size_t)icc * ICC_STRIDE;
            #pragma unroll
            for (int q = 0; q < 3; ++q)
                lo3[q] = *reinterpret_cast<const short8*>(wrlo + coff + wb[q]);
            const size_t noff = (size_t)(icc < 5 ? icc + 1 : 5) * ICC_STRIDE;
            #pragma unroll
            for (int q = 0; q < 3; ++q)
                nxt[q] = *reinterpret_cast<const short8*>(wrhi + noff + wb[q]);
            short8 bah[4], bal[4];
            #pragma unroll
            for (int p = 0; p < 4; ++p) {
                int off = ((wn * 4 + p) * 16 + col) * CPAD + icc * 32 + sg * 8;
                bah[p] = *reinterpret_cast<const short8*>(&xhi[off]);
                bal[p] = *reinterpret_cast<const short8*>(&xlo[off]);
            }
            __builtin_amdgcn_sched_barrier(0);
            #pragma unroll
            for (int j = 0; j < 3; ++j)
            #pragma unroll
            for (int p = 0; p < 4; ++p)
                a2[j][p] = __builtin_amdgcn_mfma_f32_16x16x32_bf16(
                    cur[j], bah[p], a2[j][p], 0, 0, 0);
            #pragma unroll
            for (int j = 0; j < 3; ++j)
            #pragma unroll
            for (int p = 0; p < 4; ++p)
                a2[j][p] = __builtin_amdgcn_mfma_f32_16x16x32_bf16(
                    lo3[j], bah[p], a2[j][p], 0, 0, 0);
            #pragma unroll
            for (int j = 0; j < 3; ++j)
            #pragma unroll
            for (int p = 0; p < 4; ++p)
                a2[j][p] = __builtin_amdgcn_mfma_f32_16x16x32_bf16(
                    cur[j], bal[p], a2[j][p], 0, 0, 0);
        };

        #pragma unroll
        for (int ih = 0; ih < 3; ++ih) {
            r1step(2 * ih,     rA, rB);
            r1step(2 * ih + 1, rB, rA);
        }

        // ---- mini-epilogue for this phase ----
        #pragma unroll
        for (int p = 0; p < 4; ++p) {
            const int tt = (wn * 4 + p) * 16 + col;
            const int t  = t0 + tt;
            #pragma unroll
            for (int j = 0; j < 3; ++j) {
                const int ch = (wm * 3 + j) * 16 + sg * 4;
                if constexpr (LAST) {
                    float* op = o + ((size_t)b * C + ch) * T + t;
                    #pragma unroll
                    for (int i = 0; i < 4; ++i)
                        op[(size_t)i * T] = (op[(size_t)i * T] + a2[j][p][i]) * mv[p];
                } else if (h == 0) {
                    // residual x update
                    short4v h4, l4;
                    #pragma unroll
                    for (int i = 0; i < 4; ++i) {
                        float nx = (xres[j][p][i] + a2[j][p][i]) * mv[p];
                        short hh = f2bf(nx);
                        h4[i] = hh;
                        l4[i] = f2bf(nx - bf2f(hh));
                    }
                    size_t off = (size_t)b * T * C + (size_t)t * C + ch;
                    *reinterpret_cast<short4v*>(xhout + off) = h4;
                    *reinterpret_cast<short4v*>(xlout + off) = l4;
                } else {
                    // skip accumulation
                    float* op = o + ((size_t)b * C + ch) * T + t;
                    #pragma unroll
                    for (int i = 0; i < 4; ++i) {
                        if constexpr (FIRST) op[(size_t)i * T] = a2[j][p][i];
                        else                 op[(size_t)i * T] += a2[j][p][i];
                    }
                }
            }
        }
    }
}

#define WIN_STRIDE ((size_t)5 * 24 * 6 * 64 * 8)
#define WRS_STRIDE ((size_t)24 * 6 * 64 * 8)

extern "C" void kernel_launch(void* const* d_in, const int* in_sizes, int n_in,
                              void* d_out, int out_size, void* d_ws, size_t ws_size,
                              hipStream_t stream)
{
    const float* x      = (const float*)d_in[0];
    const float* mask   = (const float*)d_in[1];
    const float* W_in   = (const float*)d_in[2];
    const float* b_in   = (const float*)d_in[3];
    const float* W_rs   = (const float*)d_in[4];
    const float* b_rs   = (const float*)d_in[5];
    const float* W_last = (const float*)d_in[6];
    const float* b_last = (const float*)d_in[7];
    float* o = (float*)d_out;

    const size_t WIN_N = (size_t)L * WIN_STRIDE;
    const size_t WRS_N = (size_t)(L - 1) * WRS_STRIDE;
    const size_t WL_N  = (size_t)12 * 6 * 64 * 8;
    const size_t P     = (size_t)BATCH * T * C;      // plane elems (shorts)
    short* wchi = (short*)d_ws;
    short* wclo = wchi + WIN_N;
    short* wrhi = wclo + WIN_N;
    short* wrlo = wrhi + WRS_N;
    short* wlhi = wrlo + WRS_N;
    short* wllo = wlhi + WL_N;
    short* xah  = wllo + WL_N;
    short* xal  = xah + P;
    short* xbh  = xal + P;
    short* xbl  = xbh + P;

    {
        int tw = (int)(L * 5 * 24 * 6 * 64);
        fmt_win<<<(tw + 255) / 256, 256, 0, stream>>>(W_in, wchi, wclo, tw);
        int tr = (int)((L - 1) * 24 * 6 * 64);
        fmt_w11<<<(tr + 255) / 256, 256, 0, stream>>>(W_rs, wrhi, wrlo, 24, tr);
        int tl = (int)(12 * 6 * 64);
        fmt_w11<<<(tl + 255) / 256, 256, 0, stream>>>(W_last, wlhi, wllo, 12, tl);
        xpose<<<dim3(T / 64, BATCH), 256, 0, stream>>>(x, xah, xal);
    }

    (void)hipFuncSetAttribute(reinterpret_cast<const void*>(&wnet_layer<true, false>),
                              hipFuncAttributeMaxDynamicSharedMemorySize, SMEM_BYTES);
    (void)hipFuncSetAttribute(reinterpret_cast<const void*>(&wnet_layer<false, false>),
                              hipFuncAttributeMaxDynamicSharedMemorySize, SMEM_BYTES);
    (void)hipFuncSetAttribute(reinterpret_cast<const void*>(&wnet_layer<false, true>),
                              hipFuncAttributeMaxDynamicSharedMemorySize, SMEM_BYTES);

    dim3 grid(T / NT, BATCH);
    dim3 block(512);

    short* curh = xah; short* curl = xal;
    short* nxth = xbh; short* nxtl = xbl;

    wnet_layer<true, false><<<grid, block, SMEM_BYTES, stream>>>(
        curh, curl, nxth, nxtl, mask,
        wchi, wclo, b_in, wrhi, wrlo, b_rs, o);
    { short* t1 = curh; curh = nxth; nxth = t1;
      short* t2 = curl; curl = nxtl; nxtl = t2; }

    for (int i = 1; i < L - 1; ++i) {
        wnet_layer<false, false><<<grid, block, SMEM_BYTES, stream>>>(
            curh, curl, nxth, nxtl, mask,
            wchi + (size_t)i * WIN_STRIDE, wclo + (size_t)i * WIN_STRIDE,
            b_in + (size_t)i * 2 * C,
            wrhi + (size_t)i * WRS_STRIDE, wrlo + (size_t)i * WRS_STRIDE,
            b_rs + (size_t)i * 2 * C, o);
        { short* t1 = curh; curh = nxth; nxth = t1;
          short* t2 = curl; curl = nxtl; nxtl = t2; }
    }

    wnet_layer<false, true><<<grid, block, SMEM_BYTES, stream>>>(
        curh, curl, nullptr, nullptr, mask,
        wchi + (size_t)(L - 1) * WIN_STRIDE, wclo + (size_t)(L - 1) * WIN_STRIDE,
        b_in + (size_t)(L - 1) * 2 * C,
        wlhi, wllo, b_last, o);
}

// Round 11
// 2498.024 us; speedup vs baseline: 1.3502x; 1.0532x over previous
//
#include <hip/hip_runtime.h>
#include <hip/hip_bf16.h>

#define C 192
#define T 4096
#define L 16
#define BATCH 16
#define NT 64          // t-positions per block
#define XR 72          // x tile rows incl. halo 4+4
#define CPAD 200       // padded channel stride in LDS (shorts) -> 400B rows (bank-spread)
#define SMEM_BYTES (2 * XR * CPAD * 2)   // xhi + xlo: 57,600 B -> 2 blocks/CU

#define CONV_TAP_STRIDE 73728   // elems: 24*6*512
#define MT_STRIDE       3072    // 6*512
#define ICC_STRIDE      512

typedef __attribute__((ext_vector_type(8))) short short8;
typedef __attribute__((ext_vector_type(4))) short short4v;
typedef __attribute__((ext_vector_type(4))) float f32x4;

__device__ __forceinline__ short f2bf(float v) {
    __hip_bfloat16 h = __float2bfloat16(v);
    return *reinterpret_cast<const short*>(&h);
}
__device__ __forceinline__ float bf2f(short s) {
    unsigned u = ((unsigned)(unsigned short)s) << 16;
    float f;
    __builtin_memcpy(&f, &u, 4);
    return f;
}

__device__ __forceinline__ float gatefn(float x1, float x2) {
    float ax = fabsf(x1);
    float e  = __expf(-2.f * ax);
    float th = __builtin_copysignf((1.f - e) / (1.f + e), x1);
    float sg = 1.f / (1.f + __expf(-x2));
    return th * sg;
}

// ---- weight pre-format with hi/lo bf16 split (Dekker: v-hi exact in fp32) ----
__global__ __launch_bounds__(256)
void fmt_win(const float* __restrict__ W, short* __restrict__ dhi,
             short* __restrict__ dlo, int total) {
    int gid = blockIdx.x * 256 + threadIdx.x;
    if (gid >= total) return;
    int lane = gid & 63; int r = gid >> 6;
    int icc = r % 6; r /= 6;
    int mt  = r % 24; r /= 24;
    int tap = r % 5;  int l = r / 5;
    int oc  = mt * 16 + (lane & 15);
    int ic0 = icc * 32 + (lane >> 4) * 8;
    const float* s = W + ((size_t)((l * 384 + oc) * 192 + ic0)) * 5 + tap;
    short8 vh, vl;
    #pragma unroll
    for (int i = 0; i < 8; ++i) {
        float v = s[(size_t)i * 5];
        short h = f2bf(v);
        vh[i] = h;
        vl[i] = f2bf(v - bf2f(h));
    }
    *reinterpret_cast<short8*>(dhi + (size_t)gid * 8) = vh;
    *reinterpret_cast<short8*>(dlo + (size_t)gid * 8) = vl;
}

__global__ __launch_bounds__(256)
void fmt_w11(const float* __restrict__ W, short* __restrict__ dhi,
             short* __restrict__ dlo, int mtc, int total) {
    int gid = blockIdx.x * 256 + threadIdx.x;
    if (gid >= total) return;
    int lane = gid & 63; int r = gid >> 6;
    int icc = r % 6; r /= 6;
    int mt  = r % mtc; int l = r / mtc;
    int oc  = mt * 16 + (lane & 15);
    int ic0 = icc * 32 + (lane >> 4) * 8;
    const float* s = W + (size_t)(l * (mtc * 16) + oc) * 192 + ic0;
    short8 vh, vl;
    #pragma unroll
    for (int i = 0; i < 8; ++i) {
        float v = s[i];
        short h = f2bf(v);
        vh[i] = h;
        vl[i] = f2bf(v - bf2f(h));
    }
    *reinterpret_cast<short8*>(dhi + (size_t)gid * 8) = vh;
    *reinterpret_cast<short8*>(dlo + (size_t)gid * 8) = vl;
}

// ---- one-time transpose+split: x fp32 [b][c][t] -> hi/lo bf16 planes [b][t][c] ----
__global__ __launch_bounds__(256)
void xpose(const float* __restrict__ x, short* __restrict__ xh, short* __restrict__ xl)
{
    __shared__ float tile[C][65];
    const int t0 = blockIdx.x * 64;
    const int b  = blockIdx.y;
    const float* xg = x + (size_t)b * C * T;
    for (int idx = threadIdx.x; idx < C * 16; idx += 256) {
        int ch = idx & 15, c = idx >> 4;
        f32x4 v = *reinterpret_cast<const f32x4*>(xg + (size_t)c * T + t0 + ch * 4);
        #pragma unroll
        for (int q = 0; q < 4; ++q) tile[c][ch * 4 + q] = v[q];
    }
    __syncthreads();
    for (int idx = threadIdx.x; idx < 64 * 24; idx += 256) {
        int cc = idx % 24, t = idx / 24;
        short8 h8, l8;
        #pragma unroll
        for (int i = 0; i < 8; ++i) {
            float v = tile[cc * 8 + i][t];
            short h = f2bf(v);
            h8[i] = h;
            l8[i] = f2bf(v - bf2f(h));
        }
        size_t off = (size_t)b * T * C + (size_t)(t0 + t) * C + cc * 8;
        *reinterpret_cast<short8*>(xh + off) = h8;
        *reinterpret_cast<short8*>(xl + off) = l8;
    }
}

// ---- fused WaveNet layer: x master is hi/lo bf16 [b][t][c] planes in ws ----
// 4 waves (256 thr): wm=wid owns 6 mt (3 gate pairs) x p=4 nt-subtiles.
// 57.6 KB LDS -> 2 blocks/CU resident: independent barrier domains de-phase,
// so one block's stage/gate/epilogue overlaps the other's MFMA (m114).
// __launch_bounds__(256,2): 2 waves/EU -> 256-VGPR budget for the pipeline.
template<bool FIRST, bool LAST>
__global__ __launch_bounds__(256, 2)
void wnet_layer(const short* __restrict__ xhin, const short* __restrict__ xlin,
                short* __restrict__ xhout, short* __restrict__ xlout,
                const float* __restrict__ mask,
                const short* __restrict__ wchi, const short* __restrict__ wclo,
                const float* __restrict__ bc,
                const short* __restrict__ wrhi, const short* __restrict__ wrlo,
                const float* __restrict__ br,
                float* __restrict__ o)
{
    extern __shared__ __align__(16) char smem_raw[];
    short* xhi = reinterpret_cast<short*>(smem_raw);
    short* xlo = xhi + XR * CPAD;

    const int tid = threadIdx.x;
    const int t0  = blockIdx.x * NT;
    const int b   = blockIdx.y;

    // ---- stage: pure 16B vector copies ----
    {
        const short* gh = xhin + (size_t)b * T * C;
        const short* gl = xlin + (size_t)b * T * C;
        for (int idx = tid; idx < 2 * XR * 24; idx += 256) {
            int chunk = idx % 24;
            int r     = (idx / 24) % XR;
            int plane = idx / (24 * XR);
            int t = t0 - 4 + r;
            short8 v = {};
            if (t >= 0 && t < T)
                v = *reinterpret_cast<const short8*>(
                        (plane ? gl : gh) + (size_t)t * C + chunk * 8);
            *reinterpret_cast<short8*>((plane ? xlo : xhi) + r * CPAD + chunk * 8) = v;
        }
    }
    __syncthreads();

    const int lane = tid & 63;
    const int wm   = tid >> 6;      // 0..3
    const int col  = lane & 15;
    const int sg   = lane >> 4;

    // per-(h*3+j) weight element offsets (sans tap/icc)
    int wbase[6];
    #pragma unroll
    for (int q = 0; q < 6; ++q) {
        int h = q / 3, j = q % 3;
        int mt = h * 12 + wm * 3 + j;
        wbase[q] = mt * MT_STRIDE + lane * 8;
    }

    // ---- conv K5, 3-pass Dekker split, pinned pipeline ----
    f32x4 acc[3][2][4];
    #pragma unroll
    for (int j = 0; j < 3; ++j)
    #pragma unroll
    for (int h = 0; h < 2; ++h) {
        f32x4 bv = *reinterpret_cast<const f32x4*>(bc + (h * 12 + wm * 3 + j) * 16 + sg * 4);
        #pragma unroll
        for (int p = 0; p < 4; ++p) acc[j][h][p] = bv;
    }

    short8 hA[6], hB[6];
    #pragma unroll
    for (int q = 0; q < 6; ++q)
        hA[q] = *reinterpret_cast<const short8*>(wchi + wbase[q]);   // (tap0,icc0)

    auto convstep = [&](int icc, short8 (&curH)[6], short8 (&nxtH)[6],
                        size_t tapoff, size_t ntapoff, int tap) {
        // 1. demand lo for this step (consumed in pass 2; pass 1 covers latency)
        short8 lo6[6];
        const size_t coff = tapoff + (size_t)icc * ICC_STRIDE;
        #pragma unroll
        for (int q = 0; q < 6; ++q)
            lo6[q] = *reinterpret_cast<const short8*>(wclo + coff + wbase[q]);
        // 2. prefetch next step's hi
        const size_t noff = (icc == 5) ? ntapoff : coff + ICC_STRIDE;
        #pragma unroll
        for (int q = 0; q < 6; ++q)
            nxtH[q] = *reinterpret_cast<const short8*>(wchi + noff + wbase[q]);
        // 3. b-frags (LDS)
        short8 bh[4], bl[4];
        #pragma unroll
        for (int p = 0; p < 4; ++p) {
            int off = (p * 16 + col + tap + 2) * CPAD + icc * 32 + sg * 8;
            bh[p] = *reinterpret_cast<const short8*>(&xhi[off]);
            bl[p] = *reinterpret_cast<const short8*>(&xlo[off]);
        }
        // pin: loads above, MFMAs below
        __builtin_amdgcn_sched_barrier(0);
        __builtin_amdgcn_s_setprio(1);
        #pragma unroll
        for (int h = 0; h < 2; ++h)
        #pragma unroll
        for (int j = 0; j < 3; ++j)
        #pragma unroll
        for (int p = 0; p < 4; ++p)
            acc[j][h][p] = __builtin_amdgcn_mfma_f32_16x16x32_bf16(
                curH[h * 3 + j], bh[p], acc[j][h][p], 0, 0, 0);
        #pragma unroll
        for (int h = 0; h < 2; ++h)
        #pragma unroll
        for (int j = 0; j < 3; ++j)
        #pragma unroll
        for (int p = 0; p < 4; ++p)
            acc[j][h][p] = __builtin_amdgcn_mfma_f32_16x16x32_bf16(
                lo6[h * 3 + j], bh[p], acc[j][h][p], 0, 0, 0);
        #pragma unroll
        for (int h = 0; h < 2; ++h)
        #pragma unroll
        for (int j = 0; j < 3; ++j)
        #pragma unroll
        for (int p = 0; p < 4; ++p)
            acc[j][h][p] = __builtin_amdgcn_mfma_f32_16x16x32_bf16(
                curH[h * 3 + j], bl[p], acc[j][h][p], 0, 0, 0);
        __builtin_amdgcn_s_setprio(0);
    };

    for (int tap = 0; tap < 5; ++tap) {
        const size_t tapoff  = (size_t)tap * CONV_TAP_STRIDE;
        const size_t ntapoff = (size_t)(tap < 4 ? tap + 1 : 4) * CONV_TAP_STRIDE;
        #pragma unroll
        for (int ih = 0; ih < 3; ++ih) {
            convstep(2 * ih,     hA, hB, tapoff, ntapoff, tap);
            convstep(2 * ih + 1, hB, hA, tapoff, ntapoff, tap);
        }
    }

    // ---- residual x pre-read from LDS (before acts overwrite) ----
    float xres[3][4][4];
    if constexpr (!LAST) {
        #pragma unroll
        for (int p = 0; p < 4; ++p) {
            const int row = p * 16 + col + 4;
            #pragma unroll
            for (int j = 0; j < 3; ++j) {
                const int ch = (wm * 3 + j) * 16 + sg * 4;
                short4v h4 = *reinterpret_cast<const short4v*>(&xhi[row * CPAD + ch]);
                short4v l4 = *reinterpret_cast<const short4v*>(&xlo[row * CPAD + ch]);
                #pragma unroll
                for (int i = 0; i < 4; ++i) xres[j][p][i] = bf2f(h4[i]) + bf2f(l4[i]);
            }
        }
    }
    __syncthreads();   // conv + residual LDS reads done before acts overwrite

    // ---- gate -> acts hi/lo (reuse xhi/xlo, rows [0,NT)) ----
    #pragma unroll
    for (int j = 0; j < 3; ++j)
    #pragma unroll
    for (int p = 0; p < 4; ++p) {
        const int tt = p * 16 + col;
        const int ch = (wm * 3 + j) * 16 + sg * 4;
        float av[4];
        #pragma unroll
        for (int i = 0; i < 4; ++i)
            av[i] = gatefn(acc[j][0][p][i], acc[j][1][p][i]);
        #pragma unroll
        for (int i2 = 0; i2 < 2; ++i2) {
            short h0 = f2bf(av[i2 * 2]);
            short h1 = f2bf(av[i2 * 2 + 1]);
            short l0 = f2bf(av[i2 * 2]     - bf2f(h0));
            short l1 = f2bf(av[i2 * 2 + 1] - bf2f(h1));
            unsigned ph = (unsigned)(unsigned short)h0 | ((unsigned)(unsigned short)h1 << 16);
            unsigned pl = (unsigned)(unsigned short)l0 | ((unsigned)(unsigned short)l1 << 16);
            *reinterpret_cast<unsigned*>(&xhi[tt * CPAD + ch + i2 * 2]) = ph;
            *reinterpret_cast<unsigned*>(&xlo[tt * CPAD + ch + i2 * 2]) = pl;
        }
    }
    __syncthreads();

    // ---- 1x1 (3-pass split), two sequential h-phases, pinned pipeline ----
    const float* mb = mask + (size_t)b * T;
    float mv[4];
    #pragma unroll
    for (int p = 0; p < 4; ++p) mv[p] = mb[t0 + p * 16 + col];

    constexpr int HN = LAST ? 1 : 2;
    #pragma unroll
    for (int h = 0; h < HN; ++h) {
        f32x4 a2[3][4];
        #pragma unroll
        for (int j = 0; j < 3; ++j) {
            f32x4 bv = *reinterpret_cast<const f32x4*>(br + (h * 12 + wm * 3 + j) * 16 + sg * 4);
            #pragma unroll
            for (int p = 0; p < 4; ++p) a2[j][p] = bv;
        }
        const int* wb = wbase + h * 3;

        short8 rA[3], rB[3];
        #pragma unroll
        for (int q = 0; q < 3; ++q)
            rA[q] = *reinterpret_cast<const short8*>(wrhi + wb[q]);   // icc=0

        auto r1step = [&](int icc, short8 (&cur)[3], short8 (&nxt)[3]) {
            short8 lo3[3];
            const size_t coff = (size_t)icc * ICC_STRIDE;
            #pragma unroll
            for (int q = 0; q < 3; ++q)
                lo3[q] = *reinterpret_cast<const short8*>(wrlo + coff + wb[q]);
            const size_t noff = (size_t)(icc < 5 ? icc + 1 : 5) * ICC_STRIDE;
            #pragma unroll
            for (int q = 0; q < 3; ++q)
                nxt[q] = *reinterpret_cast<const short8*>(wrhi + noff + wb[q]);
            short8 bah[4], bal[4];
            #pragma unroll
            for (int p = 0; p < 4; ++p) {
                int off = (p * 16 + col) * CPAD + icc * 32 + sg * 8;
                bah[p] = *reinterpret_cast<const short8*>(&xhi[off]);
                bal[p] = *reinterpret_cast<const short8*>(&xlo[off]);
            }
            __builtin_amdgcn_sched_barrier(0);
            __builtin_amdgcn_s_setprio(1);
            #pragma unroll
            for (int j = 0; j < 3; ++j)
            #pragma unroll
            for (int p = 0; p < 4; ++p)
                a2[j][p] = __builtin_amdgcn_mfma_f32_16x16x32_bf16(
                    cur[j], bah[p], a2[j][p], 0, 0, 0);
            #pragma unroll
            for (int j = 0; j < 3; ++j)
            #pragma unroll
            for (int p = 0; p < 4; ++p)
                a2[j][p] = __builtin_amdgcn_mfma_f32_16x16x32_bf16(
                    lo3[j], bah[p], a2[j][p], 0, 0, 0);
            #pragma unroll
            for (int j = 0; j < 3; ++j)
            #pragma unroll
            for (int p = 0; p < 4; ++p)
                a2[j][p] = __builtin_amdgcn_mfma_f32_16x16x32_bf16(
                    cur[j], bal[p], a2[j][p], 0, 0, 0);
            __builtin_amdgcn_s_setprio(0);
        };

        #pragma unroll
        for (int ih = 0; ih < 3; ++ih) {
            r1step(2 * ih,     rA, rB);
            r1step(2 * ih + 1, rB, rA);
        }

        // ---- mini-epilogue for this phase ----
        #pragma unroll
        for (int p = 0; p < 4; ++p) {
            const int tt = p * 16 + col;
            const int t  = t0 + tt;
            #pragma unroll
            for (int j = 0; j < 3; ++j) {
                const int ch = (wm * 3 + j) * 16 + sg * 4;
                if constexpr (LAST) {
                    float* op = o + ((size_t)b * C + ch) * T + t;
                    #pragma unroll
                    for (int i = 0; i < 4; ++i)
                        op[(size_t)i * T] = (op[(size_t)i * T] + a2[j][p][i]) * mv[p];
                } else if (h == 0) {
                    short4v h4, l4;
                    #pragma unroll
                    for (int i = 0; i < 4; ++i) {
                        float nx = (xres[j][p][i] + a2[j][p][i]) * mv[p];
                        short hh = f2bf(nx);
                        h4[i] = hh;
                        l4[i] = f2bf(nx - bf2f(hh));
                    }
                    size_t off = (size_t)b * T * C + (size_t)t * C + ch;
                    *reinterpret_cast<short4v*>(xhout + off) = h4;
                    *reinterpret_cast<short4v*>(xlout + off) = l4;
                } else {
                    float* op = o + ((size_t)b * C + ch) * T + t;
                    #pragma unroll
                    for (int i = 0; i < 4; ++i) {
                        if constexpr (FIRST) op[(size_t)i * T] = a2[j][p][i];
                        else                 op[(size_t)i * T] += a2[j][p][i];
                    }
                }
            }
        }
    }
}

#define WIN_STRIDE ((size_t)5 * 24 * 6 * 64 * 8)
#define WRS_STRIDE ((size_t)24 * 6 * 64 * 8)

extern "C" void kernel_launch(void* const* d_in, const int* in_sizes, int n_in,
                              void* d_out, int out_size, void* d_ws, size_t ws_size,
                              hipStream_t stream)
{
    const float* x      = (const float*)d_in[0];
    const float* mask   = (const float*)d_in[1];
    const float* W_in   = (const float*)d_in[2];
    const float* b_in   = (const float*)d_in[3];
    const float* W_rs   = (const float*)d_in[4];
    const float* b_rs   = (const float*)d_in[5];
    const float* W_last = (const float*)d_in[6];
    const float* b_last = (const float*)d_in[7];
    float* o = (float*)d_out;

    const size_t WIN_N = (size_t)L * WIN_STRIDE;
    const size_t WRS_N = (size_t)(L - 1) * WRS_STRIDE;
    const size_t WL_N  = (size_t)12 * 6 * 64 * 8;
    const size_t P     = (size_t)BATCH * T * C;      // plane elems (shorts)
    short* wchi = (short*)d_ws;
    short* wclo = wchi + WIN_N;
    short* wrhi = wclo + WIN_N;
    short* wrlo = wrhi + WRS_N;
    short* wlhi = wrlo + WRS_N;
    short* wllo = wlhi + WL_N;
    short* xah  = wllo + WL_N;
    short* xal  = xah + P;
    short* xbh  = xal + P;
    short* xbl  = xbh + P;

    {
        int tw = (int)(L * 5 * 24 * 6 * 64);
        fmt_win<<<(tw + 255) / 256, 256, 0, stream>>>(W_in, wchi, wclo, tw);
        int tr = (int)((L - 1) * 24 * 6 * 64);
        fmt_w11<<<(tr + 255) / 256, 256, 0, stream>>>(W_rs, wrhi, wrlo, 24, tr);
        int tl = (int)(12 * 6 * 64);
        fmt_w11<<<(tl + 255) / 256, 256, 0, stream>>>(W_last, wlhi, wllo, 12, tl);
        xpose<<<dim3(T / 64, BATCH), 256, 0, stream>>>(x, xah, xal);
    }

    (void)hipFuncSetAttribute(reinterpret_cast<const void*>(&wnet_layer<true, false>),
                              hipFuncAttributeMaxDynamicSharedMemorySize, SMEM_BYTES);
    (void)hipFuncSetAttribute(reinterpret_cast<const void*>(&wnet_layer<false, false>),
                              hipFuncAttributeMaxDynamicSharedMemorySize, SMEM_BYTES);
    (void)hipFuncSetAttribute(reinterpret_cast<const void*>(&wnet_layer<false, true>),
                              hipFuncAttributeMaxDynamicSharedMemorySize, SMEM_BYTES);

    dim3 grid(T / NT, BATCH);
    dim3 block(256);

    short* curh = xah; short* curl = xal;
    short* nxth = xbh; short* nxtl = xbl;

    wnet_layer<true, false><<<grid, block, SMEM_BYTES, stream>>>(
        curh, curl, nxth, nxtl, mask,
        wchi, wclo, b_in, wrhi, wrlo, b_rs, o);
    { short* t1 = curh; curh = nxth; nxth = t1;
      short* t2 = curl; curl = nxtl; nxtl = t2; }

    for (int i = 1; i < L - 1; ++i) {
        wnet_layer<false, false><<<grid, block, SMEM_BYTES, stream>>>(
            curh, curl, nxth, nxtl, mask,
            wchi + (size_t)i * WIN_STRIDE, wclo + (size_t)i * WIN_STRIDE,
            b_in + (size_t)i * 2 * C,
            wrhi + (size_t)i * WRS_STRIDE, wrlo + (size_t)i * WRS_STRIDE,
            b_rs + (size_t)i * 2 * C, o);
        { short* t1 = curh; curh = nxth; nxth = t1;
          short* t2 = curl; curl = nxtl; nxtl = t2; }
    }

    wnet_layer<false, true><<<grid, block, SMEM_BYTES, stream>>>(
        curh, curl, nullptr, nullptr, mask,
        wchi + (size_t)(L - 1) * WIN_STRIDE, wclo + (size_t)(L - 1) * WIN_STRIDE,
        b_in + (size_t)(L - 1) * 2 * C,
        wlhi, wllo, b_last, o);
}

// Round 12
// 1340.407 us; speedup vs baseline: 2.5163x; 1.8636x over previous
//
#include <hip/hip_runtime.h>
#include <hip/hip_bf16.h>

#define C 192
#define T 4096
#define L 16
#define BATCH 16
#define NT 64          // t-positions per block
#define XR 72          // x tile rows incl. halo 4+4
#define CPAD 200       // padded channel stride in LDS (halfs) -> 400B rows

#define CONV_TAP_STRIDE 73728   // elems: 24*6*512
#define MT_STRIDE       3072    // 6*512
#define ICC_STRIDE      512

typedef __attribute__((ext_vector_type(8))) _Float16 half8;
typedef __attribute__((ext_vector_type(4))) _Float16 half4;
typedef __attribute__((ext_vector_type(4))) float f32x4;

__device__ __forceinline__ float gatefn(float x1, float x2) {
    float ax = fabsf(x1);
    float e  = __expf(-2.f * ax);
    float th = __builtin_copysignf((1.f - e) / (1.f + e), x1);
    float sg = 1.f / (1.f + __expf(-x2));
    return th * sg;
}

// ---- weight pre-format, single fp16 plane, MFMA A-frag order ----
// gid = ((((l*5+tap)*24+mt)*6+icc)*64+lane); oc = mt*16+(lane&15), ic = icc*32+(lane>>4)*8+i
__global__ __launch_bounds__(256)
void fmt_win(const float* __restrict__ W, _Float16* __restrict__ dst, int total) {
    int gid = blockIdx.x * 256 + threadIdx.x;
    if (gid >= total) return;
    int lane = gid & 63; int r = gid >> 6;
    int icc = r % 6; r /= 6;
    int mt  = r % 24; r /= 24;
    int tap = r % 5;  int l = r / 5;
    int oc  = mt * 16 + (lane & 15);
    int ic0 = icc * 32 + (lane >> 4) * 8;
    const float* s = W + ((size_t)((l * 384 + oc) * 192 + ic0)) * 5 + tap;
    half8 v;
    #pragma unroll
    for (int i = 0; i < 8; ++i) v[i] = (_Float16)s[(size_t)i * 5];
    *reinterpret_cast<half8*>(dst + (size_t)gid * 8) = v;
}

__global__ __launch_bounds__(256)
void fmt_w11(const float* __restrict__ W, _Float16* __restrict__ dst, int mtc, int total) {
    int gid = blockIdx.x * 256 + threadIdx.x;
    if (gid >= total) return;
    int lane = gid & 63; int r = gid >> 6;
    int icc = r % 6; r /= 6;
    int mt  = r % mtc; int l = r / mtc;
    int oc  = mt * 16 + (lane & 15);
    int ic0 = icc * 32 + (lane >> 4) * 8;
    const float* s = W + (size_t)(l * (mtc * 16) + oc) * 192 + ic0;
    half8 v;
    #pragma unroll
    for (int i = 0; i < 8; ++i) v[i] = (_Float16)s[i];
    *reinterpret_cast<half8*>(dst + (size_t)gid * 8) = v;
}

// ---- one-time transpose+split: x fp32 [b][c][t] -> fp16 hi/lo planes [b][t][c] ----
// Master = hi+lo (fp16 Dekker pair, ~22-bit): storage adds no error source.
__global__ __launch_bounds__(256)
void xpose(const float* __restrict__ x, _Float16* __restrict__ xh, _Float16* __restrict__ xl)
{
    __shared__ float tile[C][65];
    const int t0 = blockIdx.x * 64;
    const int b  = blockIdx.y;
    const float* xg = x + (size_t)b * C * T;
    for (int idx = threadIdx.x; idx < C * 16; idx += 256) {
        int ch = idx & 15, c = idx >> 4;
        f32x4 v = *reinterpret_cast<const f32x4*>(xg + (size_t)c * T + t0 + ch * 4);
        #pragma unroll
        for (int q = 0; q < 4; ++q) tile[c][ch * 4 + q] = v[q];
    }
    __syncthreads();
    for (int idx = threadIdx.x; idx < 64 * 24; idx += 256) {
        int cc = idx % 24, t = idx / 24;
        half8 h8, l8;
        #pragma unroll
        for (int i = 0; i < 8; ++i) {
            float v = tile[cc * 8 + i][t];
            _Float16 h = (_Float16)v;
            h8[i] = h;
            l8[i] = (_Float16)(v - (float)h);
        }
        size_t off = (size_t)b * T * C + (size_t)(t0 + t) * C + cc * 8;
        *reinterpret_cast<half8*>(xh + off) = h8;
        *reinterpret_cast<half8*>(xl + off) = l8;
    }
}

// ---- fused WaveNet layer, single-pass fp16 MFMA ----
// 4 waves (256 thr): wm=wid owns 6 mt (3 gate pairs) x p=4 nt-subtiles.
// 28.8 KB LDS (hi plane only) -> 4+ de-phased blocks/CU.
template<bool FIRST, bool LAST>
__global__ __launch_bounds__(256, 2)
void wnet_layer(const _Float16* __restrict__ xhin, const _Float16* __restrict__ xlin,
                _Float16* __restrict__ xhout, _Float16* __restrict__ xlout,
                const float* __restrict__ mask,
                const _Float16* __restrict__ wc,   // conv weights fp16
                const float* __restrict__ bc,
                const _Float16* __restrict__ wr,   // 1x1 weights fp16
                const float* __restrict__ br,
                float* __restrict__ o)
{
    __shared__ __align__(16) _Float16 xhi[XR * CPAD];   // 28,800 B

    const int tid = threadIdx.x;
    const int t0  = blockIdx.x * NT;
    const int b   = blockIdx.y;

    // ---- stage hi plane: pure 16B vector copies ----
    {
        const _Float16* gh = xhin + (size_t)b * T * C;
        for (int idx = tid; idx < XR * 24; idx += 256) {
            int chunk = idx % 24;
            int r     = idx / 24;
            int t = t0 - 4 + r;
            half8 v = {};
            if (t >= 0 && t < T)
                v = *reinterpret_cast<const half8*>(gh + (size_t)t * C + chunk * 8);
            *reinterpret_cast<half8*>(&xhi[r * CPAD + chunk * 8]) = v;
        }
    }
    __syncthreads();

    const int lane = tid & 63;
    const int wm   = tid >> 6;      // 0..3
    const int col  = lane & 15;
    const int sg   = lane >> 4;

    int wbase[6];
    #pragma unroll
    for (int q = 0; q < 6; ++q) {
        int h = q / 3, j = q % 3;
        int mt = h * 12 + wm * 3 + j;
        wbase[q] = mt * MT_STRIDE + lane * 8;
    }

    // ---- conv K5, single pass, dbuf weight pipeline ----
    f32x4 acc[3][2][4];
    #pragma unroll
    for (int j = 0; j < 3; ++j)
    #pragma unroll
    for (int h = 0; h < 2; ++h) {
        f32x4 bv = *reinterpret_cast<const f32x4*>(bc + (h * 12 + wm * 3 + j) * 16 + sg * 4);
        #pragma unroll
        for (int p = 0; p < 4; ++p) acc[j][h][p] = bv;
    }

    half8 hA[6], hB[6];
    #pragma unroll
    for (int q = 0; q < 6; ++q)
        hA[q] = *reinterpret_cast<const half8*>(wc + wbase[q]);   // (tap0,icc0)

    auto convstep = [&](int icc, half8 (&curH)[6], half8 (&nxtH)[6],
                        size_t tapoff, size_t ntapoff, int tap) {
        const size_t coff = tapoff + (size_t)icc * ICC_STRIDE;
        const size_t noff = (icc == 5) ? ntapoff : coff + ICC_STRIDE;
        #pragma unroll
        for (int q = 0; q < 6; ++q)
            nxtH[q] = *reinterpret_cast<const half8*>(wc + noff + wbase[q]);
        half8 bh[4];
        #pragma unroll
        for (int p = 0; p < 4; ++p) {
            int off = (p * 16 + col + tap + 2) * CPAD + icc * 32 + sg * 8;
            bh[p] = *reinterpret_cast<const half8*>(&xhi[off]);
        }
        __builtin_amdgcn_sched_barrier(0);
        __builtin_amdgcn_s_setprio(1);
        #pragma unroll
        for (int h = 0; h < 2; ++h)
        #pragma unroll
        for (int j = 0; j < 3; ++j)
        #pragma unroll
        for (int p = 0; p < 4; ++p)
            acc[j][h][p] = __builtin_amdgcn_mfma_f32_16x16x32_f16(
                curH[h * 3 + j], bh[p], acc[j][h][p], 0, 0, 0);
        __builtin_amdgcn_s_setprio(0);
    };

    for (int tap = 0; tap < 5; ++tap) {
        const size_t tapoff  = (size_t)tap * CONV_TAP_STRIDE;
        const size_t ntapoff = (size_t)(tap < 4 ? tap + 1 : 4) * CONV_TAP_STRIDE;
        #pragma unroll
        for (int ih = 0; ih < 3; ++ih) {
            convstep(2 * ih,     hA, hB, tapoff, ntapoff, tap);
            convstep(2 * ih + 1, hB, hA, tapoff, ntapoff, tap);
        }
    }

    // ---- residual x-hi pre-read from LDS (before acts overwrite) ----
    half4 xresh[3][4];
    if constexpr (!LAST) {
        #pragma unroll
        for (int p = 0; p < 4; ++p) {
            const int row = p * 16 + col + 4;
            #pragma unroll
            for (int j = 0; j < 3; ++j) {
                const int ch = (wm * 3 + j) * 16 + sg * 4;
                xresh[j][p] = *reinterpret_cast<const half4*>(&xhi[row * CPAD + ch]);
            }
        }
    }
    __syncthreads();   // conv + residual LDS reads done before acts overwrite

    // ---- gate -> acts fp16 (reuse xhi rows [0,NT)) ----
    #pragma unroll
    for (int j = 0; j < 3; ++j)
    #pragma unroll
    for (int p = 0; p < 4; ++p) {
        const int tt = p * 16 + col;
        const int ch = (wm * 3 + j) * 16 + sg * 4;
        half4 av;
        #pragma unroll
        for (int i = 0; i < 4; ++i)
            av[i] = (_Float16)gatefn(acc[j][0][p][i], acc[j][1][p][i]);
        *reinterpret_cast<half4*>(&xhi[tt * CPAD + ch]) = av;
    }
    __syncthreads();

    // ---- 1x1 single pass, two sequential h-phases, dbuf pipeline ----
    const float* mb = mask + (size_t)b * T;
    float mv[4];
    #pragma unroll
    for (int p = 0; p < 4; ++p) mv[p] = mb[t0 + p * 16 + col];

    constexpr int HN = LAST ? 1 : 2;
    #pragma unroll
    for (int h = 0; h < HN; ++h) {
        f32x4 a2[3][4];
        #pragma unroll
        for (int j = 0; j < 3; ++j) {
            f32x4 bv = *reinterpret_cast<const f32x4*>(br + (h * 12 + wm * 3 + j) * 16 + sg * 4);
            #pragma unroll
            for (int p = 0; p < 4; ++p) a2[j][p] = bv;
        }
        const int* wb = wbase + h * 3;

        half8 rA[3], rB[3];
        #pragma unroll
        for (int q = 0; q < 3; ++q)
            rA[q] = *reinterpret_cast<const half8*>(wr + wb[q]);   // icc=0

        auto r1step = [&](int icc, half8 (&cur)[3], half8 (&nxt)[3]) {
            const size_t noff = (size_t)(icc < 5 ? icc + 1 : 5) * ICC_STRIDE;
            #pragma unroll
            for (int q = 0; q < 3; ++q)
                nxt[q] = *reinterpret_cast<const half8*>(wr + noff + wb[q]);
            half8 bah[4];
            #pragma unroll
            for (int p = 0; p < 4; ++p) {
                int off = (p * 16 + col) * CPAD + icc * 32 + sg * 8;
                bah[p] = *reinterpret_cast<const half8*>(&xhi[off]);
            }
            __builtin_amdgcn_sched_barrier(0);
            __builtin_amdgcn_s_setprio(1);
            #pragma unroll
            for (int j = 0; j < 3; ++j)
            #pragma unroll
            for (int p = 0; p < 4; ++p)
                a2[j][p] = __builtin_amdgcn_mfma_f32_16x16x32_f16(
                    cur[j], bah[p], a2[j][p], 0, 0, 0);
            __builtin_amdgcn_s_setprio(0);
        };

        #pragma unroll
        for (int ih = 0; ih < 3; ++ih) {
            r1step(2 * ih,     rA, rB);
            r1step(2 * ih + 1, rB, rA);
        }

        // ---- mini-epilogue for this phase ----
        #pragma unroll
        for (int p = 0; p < 4; ++p) {
            const int tt = p * 16 + col;
            const int t  = t0 + tt;
            #pragma unroll
            for (int j = 0; j < 3; ++j) {
                const int ch = (wm * 3 + j) * 16 + sg * 4;
                if constexpr (LAST) {
                    float* op = o + ((size_t)b * C + ch) * T + t;
                    #pragma unroll
                    for (int i = 0; i < 4; ++i)
                        op[(size_t)i * T] = (op[(size_t)i * T] + a2[j][p][i]) * mv[p];
                } else if (h == 0) {
                    // residual x update: master = hi(LDS-preread) + lo(global)
                    size_t off = (size_t)b * T * C + (size_t)t * C + ch;
                    half4 xl4 = *reinterpret_cast<const half4*>(xlin + off);
                    half4 h4, l4;
                    #pragma unroll
                    for (int i = 0; i < 4; ++i) {
                        float xm = (float)xresh[j][p][i] + (float)xl4[i];
                        float nx = (xm + a2[j][p][i]) * mv[p];
                        _Float16 hh = (_Float16)nx;
                        h4[i] = hh;
                        l4[i] = (_Float16)(nx - (float)hh);
                    }
                    *reinterpret_cast<half4*>(xhout + off) = h4;
                    *reinterpret_cast<half4*>(xlout + off) = l4;
                } else {
                    float* op = o + ((size_t)b * C + ch) * T + t;
                    #pragma unroll
                    for (int i = 0; i < 4; ++i) {
                        if constexpr (FIRST) op[(size_t)i * T] = a2[j][p][i];
                        else                 op[(size_t)i * T] += a2[j][p][i];
                    }
                }
            }
        }
    }
}

#define WIN_STRIDE ((size_t)5 * 24 * 6 * 64 * 8)
#define WRS_STRIDE ((size_t)24 * 6 * 64 * 8)

extern "C" void kernel_launch(void* const* d_in, const int* in_sizes, int n_in,
                              void* d_out, int out_size, void* d_ws, size_t ws_size,
                              hipStream_t stream)
{
    const float* x      = (const float*)d_in[0];
    const float* mask   = (const float*)d_in[1];
    const float* W_in   = (const float*)d_in[2];
    const float* b_in   = (const float*)d_in[3];
    const float* W_rs   = (const float*)d_in[4];
    const float* b_rs   = (const float*)d_in[5];
    const float* W_last = (const float*)d_in[6];
    const float* b_last = (const float*)d_in[7];
    float* o = (float*)d_out;

    const size_t WIN_N = (size_t)L * WIN_STRIDE;
    const size_t WRS_N = (size_t)(L - 1) * WRS_STRIDE;
    const size_t WL_N  = (size_t)12 * 6 * 64 * 8;
    const size_t P     = (size_t)BATCH * T * C;      // plane elems
    _Float16* wc  = (_Float16*)d_ws;
    _Float16* wr  = wc + WIN_N;
    _Float16* wl  = wr + WRS_N;
    _Float16* xah = wl + WL_N;
    _Float16* xal = xah + P;
    _Float16* xbh = xal + P;
    _Float16* xbl = xbh + P;

    {
        int tw = (int)(L * 5 * 24 * 6 * 64);
        fmt_win<<<(tw + 255) / 256, 256, 0, stream>>>(W_in, wc, tw);
        int tr = (int)((L - 1) * 24 * 6 * 64);
        fmt_w11<<<(tr + 255) / 256, 256, 0, stream>>>(W_rs, wr, 24, tr);
        int tl = (int)(12 * 6 * 64);
        fmt_w11<<<(tl + 255) / 256, 256, 0, stream>>>(W_last, wl, 12, tl);
        xpose<<<dim3(T / 64, BATCH), 256, 0, stream>>>(x, xah, xal);
    }

    dim3 grid(T / NT, BATCH);
    dim3 block(256);

    _Float16* curh = xah; _Float16* curl = xal;
    _Float16* nxth = xbh; _Float16* nxtl = xbl;

    wnet_layer<true, false><<<grid, block, 0, stream>>>(
        curh, curl, nxth, nxtl, mask,
        wc, b_in, wr, b_rs, o);
    { _Float16* t1 = curh; curh = nxth; nxth = t1;
      _Float16* t2 = curl; curl = nxtl; nxtl = t2; }

    for (int i = 1; i < L - 1; ++i) {
        wnet_layer<false, false><<<grid, block, 0, stream>>>(
            curh, curl, nxth, nxtl, mask,
            wc + (size_t)i * WIN_STRIDE, b_in + (size_t)i * 2 * C,
            wr + (size_t)i * WRS_STRIDE, b_rs + (size_t)i * 2 * C, o);
        { _Float16* t1 = curh; curh = nxth; nxth = t1;
          _Float16* t2 = curl; curl = nxtl; nxtl = t2; }
    }

    wnet_layer<false, true><<<grid, block, 0, stream>>>(
        curh, curl, nullptr, nullptr, mask,
        wc + (size_t)(L - 1) * WIN_STRIDE, b_in + (size_t)(L - 1) * 2 * C,
        wl, b_last, o);
}